// Round 9
// baseline (401.068 us; speedup 1.0000x reference)
//
#include <hip/hip_runtime.h>
#include <math.h>

// B=4, TU=2048, TM=256, D=1024, H=16, DH=64, PAIRS=512
typedef unsigned short u16;
typedef __attribute__((ext_vector_type(8))) short bf16x8;
typedef __attribute__((ext_vector_type(4))) float f32x4;

__device__ __forceinline__ float sigmoidf_(float x) { return 1.0f / (1.0f + __expf(-x)); }
__device__ __forceinline__ u16 f2bf(float v) {
    union { float f; unsigned u; } x; x.f = v;
    unsigned r = x.u + 0x7fffu + ((x.u >> 16) & 1u);
    return (u16)(r >> 16);
}
__device__ __forceinline__ float bf2f(u16 u) {
    union { unsigned u; float f; } x; x.u = ((unsigned)u) << 16; return x.f;
}

#define GLD(src, dst) __builtin_amdgcn_global_load_lds( \
        (const __attribute__((address_space(1))) void*)(src), \
        (__attribute__((address_space(3))) void*)(dst), 16, 0, 0)

// ---------------------------------------------------------------------------
// balance_norm + gate + fused pairnorm, ONE WAVE PER ROW (shuffle-only).
// Lane l owns elems [16l,16l+16): lanes<32 = first half (for the e1/e2 split).
// ---------------------------------------------------------------------------
__global__ void __launch_bounds__(256) norm_gate_kernel(
    const float* __restrict__ X,
    const float* __restrict__ w, const float* __restrict__ bvec,
    const float* __restrict__ bw_p,
    const float* __restrict__ gw, const float* __restrict__ gb_p,
    u16* __restrict__ OUT, u16* __restrict__ PN, float* __restrict__ G)
{
    const int row = blockIdx.x * 4 + (threadIdx.x >> 6);
    const int lane = threadIdx.x & 63;
    const float* xr = X + (size_t)row * 1024 + lane * 16;
    float4 xa = ((const float4*)xr)[0];
    float4 xb = ((const float4*)xr)[1];
    float4 xc = ((const float4*)xr)[2];
    float4 xd = ((const float4*)xr)[3];
    float s1 = (xa.x + xa.y + xa.z + xa.w) + (xb.x + xb.y + xb.z + xb.w)
             + (xc.x + xc.y + xc.z + xc.w) + (xd.x + xd.y + xd.z + xd.w);
    float s2 = xa.x * xa.x + xa.y * xa.y + xa.z * xa.z + xa.w * xa.w
             + xb.x * xb.x + xb.y * xb.y + xb.z * xb.z + xb.w * xb.w
             + xc.x * xc.x + xc.y * xc.y + xc.z * xc.z + xc.w * xc.w
             + xd.x * xd.x + xd.y * xd.y + xd.z * xd.z + xd.w * xd.w;
    #pragma unroll
    for (int o = 1; o <= 32; o <<= 1) s1 += __shfl_xor(s1, o);
    float h2 = s2;
    #pragma unroll
    for (int o = 1; o <= 16; o <<= 1) h2 += __shfl_xor(h2, o);   // within 32-half
    const float oth = __shfl_xor(h2, 32);
    const float slo = (lane < 32) ? h2 : oth;
    const float shi = (lane < 32) ? oth : h2;
    const float mu = s1 * (1.0f / 1024.0f);
    const float var = (slo + shi) * (1.0f / 1024.0f) - mu * mu;
    const float rstd = rsqrtf(var + 1e-6f);
    const float imb = (slo - shi) * (1.0f / 512.0f) * (*bw_p);
    const float corr = (lane < 32) ? -imb : imb;
    const int i0 = lane * 16;
    const float4* wp = (const float4*)(w + i0);
    const float4* bp = (const float4*)(bvec + i0);
    const float4* gp = (const float4*)(gw + i0);
    float o16[16];
    float gd = 0.0f;
    #pragma unroll
    for (int q = 0; q < 4; ++q) {
        float4 xv = (q == 0) ? xa : (q == 1) ? xb : (q == 2) ? xc : xd;
        float4 wv = wp[q], bv = bp[q], gv = gp[q];
        float t0 = (xv.x - mu) * rstd * wv.x + bv.x + corr;
        float t1 = (xv.y - mu) * rstd * wv.y + bv.y + corr;
        float t2 = (xv.z - mu) * rstd * wv.z + bv.z + corr;
        float t3 = (xv.w - mu) * rstd * wv.w + bv.w + corr;
        gd += t0 * gv.x + t1 * gv.y + t2 * gv.z + t3 * gv.w;
        o16[4 * q + 0] = t0; o16[4 * q + 1] = t1; o16[4 * q + 2] = t2; o16[4 * q + 3] = t3;
    }
    #pragma unroll
    for (int o = 1; o <= 32; o <<= 1) gd += __shfl_xor(gd, o);
    if (lane == 0) G[row] = sigmoidf_(gd + *gb_p);
    u16 ob[16], pn[16];
    #pragma unroll
    for (int j = 0; j < 16; ++j) ob[j] = f2bf(o16[j]);
    #pragma unroll
    for (int j = 0; j < 8; ++j) {
        float px = o16[2 * j] + 1e-8f, py = o16[2 * j + 1] + 1e-8f;
        float rr = rsqrtf(px * px + py * py);
        pn[2 * j] = f2bf(px * rr); pn[2 * j + 1] = f2bf(py * rr);
    }
    *(uint4*)(OUT + (size_t)row * 1024 + i0) = *(uint4*)ob;
    *(uint4*)(OUT + (size_t)row * 1024 + i0 + 8) = *(uint4*)(ob + 8);
    *(uint4*)(PN + (size_t)row * 1024 + i0) = *(uint4*)pn;
    *(uint4*)(PN + (size_t)row * 1024 + i0 + 8) = *(uint4*)(pn + 8);
}

// ---------------------------------------------------------------------------
// weight fp32 -> bf16 (8 slots of 1M elements; order set by pointer args)
// ---------------------------------------------------------------------------
__global__ void __launch_bounds__(256) wconv_kernel(
    const float* w0, const float* w1, const float* w2, const float* w3,
    const float* w4, const float* w5, const float* w6, const float* w7,
    u16* __restrict__ dst)
{
    const float* s;
    switch (blockIdx.y) {
        case 0: s = w0; break; case 1: s = w1; break;
        case 2: s = w2; break; case 3: s = w3; break;
        case 4: s = w4; break; case 5: s = w5; break;
        case 6: s = w6; break; default: s = w7; break;
    }
    long i = (long)blockIdx.x * 1024 + threadIdx.x * 4;
    float4 v = *(const float4*)(s + i);
    u16 o[4] = { f2bf(v.x), f2bf(v.y), f2bf(v.z), f2bf(v.w) };
    *(uint2*)(dst + (long)blockIdx.y * 1048576 + i) = *(uint2*)o;
}

__global__ void __launch_bounds__(256) cvt_kernel(const float* __restrict__ S, u16* __restrict__ D)
{
    long i = ((long)blockIdx.x * 256 + threadIdx.x) * 4;
    float4 v = *(const float4*)(S + i);
    u16 o[4] = { f2bf(v.x), f2bf(v.y), f2bf(v.z), f2bf(v.w) };
    *(uint2*)(D + i) = *(uint2*)o;
}

// ---------------------------------------------------------------------------
// mfma8: 256xBN-tile bf16 NT GEMM, BK=32, 512 threads = 8 waves (2M x 4N),
// per-wave output 128 x BN/4.  RING-3 LDS, counted-vmcnt schedule (T3+T4).
// BN=128 -> 72KB LDS -> 2 blocks/CU co-residency (the latency-hiding lever).
// EPI 3: f32 base[idx]+acc*rs[row]
// EPI 6: micro fused 3-way sections (Kc bf16 | VTc transposed uint2 | Qe bf16)
// ---------------------------------------------------------------------------
template<int BN, int EPI>
__global__ void __launch_bounds__(512, 4) mfma8(
    const u16* __restrict__ A, const u16* __restrict__ B,
    void* __restrict__ C, void* __restrict__ Cx, void* __restrict__ Cy,
    int K, int lda, int ldb,
    const float* __restrict__ base, const float* __restrict__ rs)
{
    constexpr int NR = BN / 64;                 // N-frags per wave
    constexpr int RSTRIDE = 8192 + BN * 32;     // u16 per ring slot
    __shared__ __align__(16) u16 sh[3 * RSTRIDE];
    const int gx = gridDim.x, gy = gridDim.y;
    const int lin = blockIdx.x + gx * blockIdx.y;
    const int xcd = lin & 7, off = lin >> 3;
    const int lby = gy >> 3;
    const int by = xcd * lby + (off % lby);
    const int bx = off / lby;
    const int t = threadIdx.x;
    const int lane = t & 63, w = t >> 6;
    const int wm = w >> 2, wn = w & 3;
    const long m0 = (long)by * 256;
    const long n0 = (long)bx * BN;
    const int frow = lane & 15, fk = (lane >> 4) * 8;
    const u16* Ag0 = A + (m0 + w * 16 + frow) * lda + fk;
    const u16* Ag1 = Ag0 + 128L * lda;
    const u16* Bg0 = B + (n0 + w * 16 + frow) * ldb + fk;
    const u16* Bg1 = Bg0 + 128L * ldb;

    auto stage = [&](int i, int r) {
        const int k0 = i << 5;
        u16* d = sh + r * RSTRIDE;
        GLD(Ag0 + k0, d + w * 512);
        GLD(Ag1 + k0, d + (8 + w) * 512);
        GLD(Bg0 + k0, d + 8192 + w * 512);
        if constexpr (BN == 256) GLD(Bg1 + k0, d + 8192 + (8 + w) * 512);
    };

    const int nIter = K >> 5;
    f32x4 acc[8][NR] = {};
    stage(0, 0);
    stage(1, 1);
    if constexpr (BN == 256) asm volatile("s_waitcnt vmcnt(4)" ::: "memory");
    else                     asm volatile("s_waitcnt vmcnt(3)" ::: "memory");
    __builtin_amdgcn_sched_barrier(0);
    __builtin_amdgcn_s_barrier();
    int r = 0;
    for (int i = 0; i < nIter; ++i) {
        if (i + 2 < nIter) {
            int r2 = r + 2; if (r2 >= 3) r2 -= 3;
            stage(i + 2, r2);
        }
        const u16* ra = sh + r * RSTRIDE;
        bf16x8 af[8], bf[NR];
        #pragma unroll
        for (int mi = 0; mi < 8; ++mi)
            af[mi] = *(const bf16x8*)(ra + (wm * 8 + mi) * 512 + lane * 8);
        #pragma unroll
        for (int ni = 0; ni < NR; ++ni)
            bf[ni] = *(const bf16x8*)(ra + 8192 + (wn * NR + ni) * 512 + lane * 8);
        asm volatile("s_waitcnt lgkmcnt(0)" ::: "memory");
        __builtin_amdgcn_sched_barrier(0);
        __builtin_amdgcn_s_setprio(1);
        #pragma unroll
        for (int mi = 0; mi < 8; ++mi)
            #pragma unroll
            for (int ni = 0; ni < NR; ++ni)
                acc[mi][ni] = __builtin_amdgcn_mfma_f32_16x16x32_bf16(af[mi], bf[ni], acc[mi][ni], 0, 0, 0);
        __builtin_amdgcn_s_setprio(0);
        if (i + 1 < nIter) {
            if (i + 2 < nIter) {
                if constexpr (BN == 256) asm volatile("s_waitcnt vmcnt(4)" ::: "memory");
                else                     asm volatile("s_waitcnt vmcnt(3)" ::: "memory");
            } else {
                asm volatile("s_waitcnt vmcnt(0)" ::: "memory");
            }
            __builtin_amdgcn_sched_barrier(0);
            __builtin_amdgcn_s_barrier();
        }
        ++r; if (r >= 3) r = 0;
    }
    // ---- epilogue ----
    const int l15 = lane & 15, l4 = lane >> 4;
    #pragma unroll
    for (int mi = 0; mi < 8; ++mi) {
        #pragma unroll
        for (int ni = 0; ni < NR; ++ni) {
            const long grow0 = m0 + wm * 128 + mi * 16 + l4 * 4;
            const long gcol  = n0 + wn * (BN / 4) + ni * 16 + l15;
            if constexpr (EPI == 3) {
                #pragma unroll
                for (int j = 0; j < 4; ++j) {
                    const long idx = (grow0 + j) * 1024 + gcol;
                    ((float*)C)[idx] = base[idx] + acc[mi][ni][j] * rs[grow0 + j];
                }
            } else {  // EPI == 6
                const int sec = (int)(n0 >> 10);
                if (sec == 0) {
                    #pragma unroll
                    for (int j = 0; j < 4; ++j)
                        ((u16*)C)[(grow0 + j) * 1024 + gcol] = f2bf(acc[mi][ni][j]);   // K_conv
                } else if (sec == 1) {
                    const long col = gcol - 1024;
                    u16 pk[4] = { f2bf(acc[mi][ni][0]), f2bf(acc[mi][ni][1]),
                                  f2bf(acc[mi][ni][2]), f2bf(acc[mi][ni][3]) };
                    const long idx = (grow0 >> 11) * 2097152 + col * 2048 + (grow0 & 2047);
                    *(uint2*)&((u16*)Cx)[idx] = *(uint2*)pk;                            // VT_conv
                } else {
                    #pragma unroll
                    for (int j = 0; j < 4; ++j)
                        ((u16*)Cy)[(grow0 + j) * 1024 + (gcol - 2048)] = f2bf(acc[mi][ni][j]); // Q_emer
                }
            }
        }
    }
}

// ---------------------------------------------------------------------------
// bf16 NT MFMA GEMM, 128xBN tile, BK=32, 256 threads (2x2 waves).
// 3-STAGE LDS PIPELINE, 2 TILES IN FLIGHT. (unchanged)
// ---------------------------------------------------------------------------
template<int BN, int EPI, bool SWZ>
__global__ void __launch_bounds__(256) mfma_nt(
    const u16* __restrict__ A, long zAb, long zAh,
    const u16* __restrict__ B, long zBb, long zBh,
    void* __restrict__ C, long zCb, long zCh,
    void* __restrict__ Cx, void* __restrict__ Cy,
    int K, int lda, int ldb, int ldc, float alpha, int nH, int nsplit,
    const float* __restrict__ base, const float* __restrict__ rs,
    const float* __restrict__ accB, float* __restrict__ OT,
    long zOT, int ldt)
{
    constexpr int NR = BN / 32;
    constexpr int ABUF = 128 * 32;
    constexpr int BBUF = BN * 32;
    __shared__ __align__(16) u16 sh[3 * (ABUF + BBUF)];
    u16* const Ab0 = sh;
    u16* const Bb0 = sh + 3 * ABUF;
    int bx, by, bz;
    if constexpr (SWZ) {
        const int gx = gridDim.x, gy = gridDim.y;
        const int lin = blockIdx.x + gx * blockIdx.y;
        const int xcd = lin & 7, c = lin >> 3;
        const int LBY = gy >> 3;
        const int SPB = 4 * LBY;
        const int sc = c / SPB, rr = c - sc * SPB;
        const int byl = rr >> 2, bxl = rr & 3;
        by = xcd * LBY + byl;
        bx = sc * 4 + bxl;
        bz = 0;
    } else {
        bx = blockIdx.x; by = blockIdx.y; bz = blockIdx.z;
    }
    const int t = threadIdx.x;
    const int lane = t & 63, w = t >> 6;
    const int wr = w >> 1, wc = w & 1;
    const int slab = bz / nsplit, ks = bz - slab * nsplit;
    const int b = slab / nH, h = slab - b * nH;
    const int kchunk = K / nsplit;
    const int kbeg = ks * kchunk, kend = kbeg + kchunk;
    const long m0 = (long)by * 128;
    const long n0 = (long)bx * BN;
    const int frow = lane & 15, fko = (lane >> 4) * 8;
    const u16* gaA = A + zAb * b + zAh * h + (m0 + 32 * w + frow) * lda + fko;
    const u16* gbB;
    if constexpr (BN == 128) gbB = B + zBb * b + zBh * h + (n0 + 32 * w + frow) * ldb + fko;
    else                     gbB = B + zBb * b + zBh * h + (n0 + 16 * w + frow) * ldb + fko;

    auto stage = [&](int kk, int p) {
        u16* ap = Ab0 + p * ABUF;
        u16* bp = Bb0 + p * BBUF;
        GLD(gaA + kk, ap + 2 * w * 512);
        GLD(gaA + 16L * lda + kk, ap + (2 * w + 1) * 512);
        if constexpr (BN == 128) {
            GLD(gbB + kk, bp + 2 * w * 512);
            GLD(gbB + 16L * ldb + kk, bp + (2 * w + 1) * 512);
        } else {
            GLD(gbB + kk, bp + w * 512);
        }
    };

    const int nIter = (kend - kbeg) >> 5;
    f32x4 acc[4][NR] = {};
    stage(kbeg, 0);
    if (nIter > 1) stage(kbeg + 32, 1);
    int cur = 0;
    for (int i = 0; i < nIter; ++i) {
        if (i + 2 < nIter) {
            int p2 = cur + 2; if (p2 >= 3) p2 -= 3;
            stage(kbeg + (i + 2) * 32, p2);
            if constexpr (BN == 128) asm volatile("s_waitcnt vmcnt(8)" ::: "memory");
            else                     asm volatile("s_waitcnt vmcnt(6)" ::: "memory");
        } else if (i + 1 < nIter) {
            if constexpr (BN == 128) asm volatile("s_waitcnt vmcnt(4)" ::: "memory");
            else                     asm volatile("s_waitcnt vmcnt(3)" ::: "memory");
        } else {
            asm volatile("s_waitcnt vmcnt(0)" ::: "memory");
        }
        __builtin_amdgcn_sched_barrier(0);
        __builtin_amdgcn_s_barrier();
        __builtin_amdgcn_sched_barrier(0);
        const u16* ap = Ab0 + cur * ABUF;
        const u16* bp = Bb0 + cur * BBUF;
        bf16x8 af[4], bfr[NR];
        #pragma unroll
        for (int m = 0; m < 4; ++m)
            af[m] = *(const bf16x8*)(ap + (wr * 4 + m) * 512 + lane * 8);
        #pragma unroll
        for (int n = 0; n < NR; ++n)
            bfr[n] = *(const bf16x8*)(bp + (wc * NR + n) * 512 + lane * 8);
        asm volatile("s_waitcnt lgkmcnt(0)" ::: "memory");
        __builtin_amdgcn_sched_barrier(0);
        __builtin_amdgcn_s_barrier();
        #pragma unroll
        for (int m = 0; m < 4; ++m)
            #pragma unroll
            for (int n = 0; n < NR; ++n)
                acc[m][n] = __builtin_amdgcn_mfma_f32_16x16x32_bf16(af[m], bfr[n], acc[m][n], 0, 0, 0);
        cur = (cur == 2) ? 0 : cur + 1;
    }
    const long Coff = zCb * b + zCh * h;
    const int l15 = lane & 15, l4 = lane >> 4;
    if constexpr (EPI == 6 || EPI == 7) {
        constexpr int VTSEC = (EPI == 6) ? 1 : 2;
        if ((int)(n0 >> 10) == VTSEC) {
            __syncthreads();
            #pragma unroll
            for (int m = 0; m < 4; ++m)
                #pragma unroll
                for (int n = 0; n < NR; ++n)
                    #pragma unroll
                    for (int j = 0; j < 4; ++j)
                        sh[(wc * 64 + n * 16 + l15) * 136 + (wr * 64 + m * 16 + l4 * 4 + j)]
                            = f2bf(acc[m][n][j] * alpha);
            __syncthreads();
            constexpr int  LT   = (EPI == 6) ? 2048 : 256;
            constexpr int  L2T  = (EPI == 6) ? 11 : 8;
            constexpr long BSTR = (EPI == 6) ? 2097152L : 262144L;
            u16* dst = (EPI == 6) ? (u16*)Cx : (u16*)Cy;
            const long bb  = m0 >> L2T;
            const int  tt0 = (int)(m0 & (LT - 1));
            const long colb = n0 & 1023;
            #pragma unroll
            for (int it = 0; it < 8; ++it) {
                const int c = it * 16 + (t >> 4);
                const int rr = (t & 15) * 8;
                uint4 v = *(const uint4*)&sh[c * 136 + rr];
                *(uint4*)&dst[bb * BSTR + (colb + c) * LT + tt0 + rr] = v;
            }
            return;
        }
    }
    #pragma unroll
    for (int m = 0; m < 4; ++m) {
        #pragma unroll
        for (int n = 0; n < NR; ++n) {
            #pragma unroll
            for (int j = 0; j < 4; ++j) {
                const long grow = m0 + wr * 64 + m * 16 + l4 * 4 + j;
                const long gcol = n0 + wc * (BN / 2) + n * 16 + l15;
                const float v = acc[m][n][j] * alpha;
                if constexpr (EPI == 0) {
                    ((u16*)C)[Coff + grow * ldc + gcol] = f2bf(v);
                } else if constexpr (EPI == 2) {
                    atomicAdd((float*)C + Coff + grow * ldc + gcol, v);
                } else if constexpr (EPI == 3) {
                    const long idx = grow * ldc + gcol;
                    ((float*)C)[idx] = base[idx] + v * rs[grow];
                } else if constexpr (EPI == 5) {
                    const long idx = Coff + grow * ldc + gcol;
                    ((float*)C)[idx] = 0.7f * base[idx] + 0.3f * v;
                    const long tidx = zOT * b + gcol * (long)ldt + grow;
                    OT[tidx] = 0.7f * accB[tidx] + 0.3f * v;
                } else if constexpr (EPI == 6) {
                    if (n0 < 1024) ((u16*)C)[grow * 1024 + gcol] = f2bf(v);
                    else           ((u16*)Cy)[grow * 1024 + (gcol - 2048)] = f2bf(v);
                } else {  // EPI == 7
                    if (n0 < 1024) ((u16*)C)[grow * 1024 + gcol] = f2bf(v);
                    else           ((u16*)Cx)[grow * 1024 + (gcol - 1024)] = f2bf(v);
                }
            }
        }
    }
}

// ---------------------------------------------------------------------------
// softmax + gate + renorm, IN PLACE on bf16 scores; one wave per row.
// ---------------------------------------------------------------------------
template<int NU2>
__global__ void __launch_bounds__(256) softmax_gate_kernel(
    u16* __restrict__ P,
    const float* __restrict__ AG, const float* __restrict__ EG,
    int bshift, int qmask, int qld, int egld)
{
    const int row = blockIdx.x * 4 + (threadIdx.x >> 6);
    const int lane = threadIdx.x & 63;
    const int bl = row >> bshift;
    unsigned* pr = (unsigned*)(P + (long)row * (NU2 * 128));
    const float* egr = EG + (long)bl * egld;
    float r0[NU2], r1[NU2];
    float m = -3.4e38f;
    #pragma unroll
    for (int u = 0; u < NU2; ++u) {
        unsigned v = pr[lane + 64 * u];
        r0[u] = bf2f((u16)(v & 0xffffu));
        r1[u] = bf2f((u16)(v >> 16));
        m = fmaxf(m, fmaxf(r0[u], r1[u]));
    }
    for (int o = 32; o > 0; o >>= 1) m = fmaxf(m, __shfl_xor(m, o));
    float l = 0.0f, se = 0.0f;
    #pragma unroll
    for (int u = 0; u < NU2; ++u) {
        float e0 = __expf(r0[u] - m), e1 = __expf(r1[u] - m);
        l += e0 + e1;
        float2 eg = *(const float2*)(egr + 2 * (lane + 64 * u));
        r0[u] = e0 * eg.x; r1[u] = e1 * eg.y;
        se += r0[u] + r1[u];
    }
    for (int o = 32; o > 0; o >>= 1) { l += __shfl_xor(l, o); se += __shfl_xor(se, o); }
    const float ag = AG[(long)bl * qld + (row & qmask)];
    const float f = ag / (ag * se + l * 1e-8f);
    #pragma unroll
    for (int u = 0; u < NU2; ++u) {
        unsigned vo = (unsigned)f2bf(r0[u] * f) | ((unsigned)f2bf(r1[u] * f) << 16);
        pr[lane + 64 * u] = vo;
    }
}

__global__ void __launch_bounds__(256) rowmean_sig_kernel(
    const float* __restrict__ X, int len, float invlen,
    const float* __restrict__ alpha_p, float* __restrict__ OUT)
{
    const int row = blockIdx.x * 4 + (threadIdx.x >> 6);
    const int lane = threadIdx.x & 63;
    const float* xr = X + (long)row * len;
    float s = 0.0f;
    for (int k = lane; k < len; k += 64) s += xr[k];
    for (int o = 32; o > 0; o >>= 1) s += __shfl_xor(s, o);
    if (lane == 0) OUT[row] = sigmoidf_((*alpha_p) * s * invlen);
}

#define MFMA_TAIL nullptr, nullptr, nullptr, nullptr, 0L, 0

extern "C" void kernel_launch(void* const* d_in, const int* in_sizes, int n_in,
                              void* d_out, int out_size, void* d_ws, size_t ws_size,
                              hipStream_t stream)
{
    (void)in_sizes; (void)n_in; (void)out_size; (void)ws_size;
    const float* o_micro    = (const float*)d_in[0];
    const float* o_macro    = (const float*)d_in[1];
    const float* r_conv_acc = (const float*)d_in[2];
    const float* r_emer_acc = (const float*)d_in[3];
    const float* ln_u_w = (const float*)d_in[4];
    const float* ln_u_b = (const float*)d_in[5];
    const float* bw_u   = (const float*)d_in[6];
    const float* ln_m_w = (const float*)d_in[7];
    const float* ln_m_b = (const float*)d_in[8];
    const float* bw_m   = (const float*)d_in[9];
    const float* gu_w   = (const float*)d_in[10];
    const float* gu_b   = (const float*)d_in[11];
    const float* gm_w   = (const float*)d_in[12];
    const float* gm_b   = (const float*)d_in[13];
    const float* wq_c   = (const float*)d_in[14];
    const float* wk_c   = (const float*)d_in[15];
    const float* wv_c   = (const float*)d_in[16];
    const float* wo_c   = (const float*)d_in[17];
    const float* wq_e   = (const float*)d_in[18];
    const float* wk_e   = (const float*)d_in[19];
    const float* wv_e   = (const float*)d_in[20];
    const float* wo_e   = (const float*)d_in[21];
    const float* res_alpha = (const float*)d_in[22];

    float* out = (float*)d_out;
    float* out_micro = out;              // (4,2048,1024)
    float* out_macro = out + 8388608;    // (4,256,1024)
    float* out_rconv = out + 9437184;    // (4,256,2048)
    float* out_remer = out + 11534336;   // (4,2048,256)

    // workspace (f32 slot offsets; bf16 buffers use 2 el/slot)
    float* ws = (float*)d_ws;
    u16* OUb = (u16*)ws;                       // 8388608 bf16 (normed micro)
    u16* OMb = (u16*)(ws + 4194304);           // 1048576 bf16 (normed macro)
    u16* WB  = (u16*)(ws + 4718592);           // 8 x 1048576 bf16 weights
                                               //   [wk_c wv_c wq_e | wq_c wk_e wv_e | wo_c wo_e]
    u16* Kcb = (u16*)(ws + 8912896);           // conv K (8192x1024) -> later CTe
    u16* VTc = (u16*)(ws + 13107200);          // conv V^T [b][h][64][2048]
    u16* Qeb = (u16*)(ws + 17301504);          // emer Q (8192x1024)
    u16* Qcb = (u16*)(ws + 21495808);          // conv Q (1024x1024) -> later CTb
    u16* Keb = (u16*)(ws + 22020096);          // emer K (1024x1024)
    u16* VTe = (u16*)(ws + 22544384);          // emer V^T [b][h][64][256]
    u16* PNu = (u16*)(ws + 23068672);          // pairnormed micro (8.4M bf16)
    float* CT = ws + 27262976;                 // conv ctx f32 (4x256x1024); early: PNm
    float* GU = ws + 28311552;                 // 8192
    float* GM = GU + 8192;                     // 1024
    float* RCS = GM + 1024;                    // 1024
    float* RES = RCS + 1024;                   // 8192
    u16* PNm = (u16*)CT;
    u16* CTb = Qcb;
    u16* CTe = Kcb;
    u16* SCu = (u16*)out_micro;                // 2-batch bf16 score/prob slab (16.8M els)

    // 1. weights -> bf16, reordered for fused projections
    wconv_kernel<<<dim3(1024, 8), 256, 0, stream>>>(wk_c, wv_c, wq_e, wq_c, wk_e, wv_e, wo_c, wo_e, WB);
    // 2. balance norms + gates + fused pairnorm (wave-per-row)
    norm_gate_kernel<<<2048, 256, 0, stream>>>(o_micro, ln_u_w, ln_u_b, bw_u, gu_w, gu_b, OUb, PNu, GU);
    norm_gate_kernel<<<256, 256, 0, stream>>>(o_macro, ln_m_w, ln_m_b, bw_m, gm_w, gm_b, OMb, PNm, GM);
    // 3. resonance GEMM + 0.7/0.3 blend + transposed write
    mfma_nt<128, 5, false><<<dim3(16, 2, 4), 256, 0, stream>>>(
        PNm, 262144L, 0L, PNu, 2097152L, 0L, out_rconv, 524288L, 0L, nullptr, nullptr,
        1024, 1024, 1024, 2048, 1.0f / 512.0f, 1, 1,
        r_conv_acc, nullptr, r_emer_acc, out_remer, 524288L, 256);
    // 4. resonance scalars
    rowmean_sig_kernel<<<256, 256, 0, stream>>>(out_rconv, 2048, 1.0f / 2048.0f, res_alpha, RCS);
    rowmean_sig_kernel<<<2048, 256, 0, stream>>>(out_remer, 256, 1.0f / 256.0f, res_alpha, RES);
    // 5. fused micro-side projections: [K_conv | VT_conv | Q_emer]  (mfma8, 256x128, 2 blk/CU)
    mfma8<128, 6><<<dim3(24, 32), 512, 0, stream>>>(
        OUb, WB, Kcb, VTc, Qeb, 1024, 1024, 1024, nullptr, nullptr);
    // 6. fused macro-side projections: [Q_conv | K_emer | VT_emer]
    mfma_nt<128, 7, true><<<dim3(24, 8, 1), 256, 0, stream>>>(
        OMb, 0L, 0L, WB + 3 * 1048576, 0L, 0L, Qcb, 0L, 0L, Keb, VTe,
        1024, 1024, 1024, 1024, 1.0f, 1, 1, MFMA_TAIL);
    // 7. conv ctx accumulator
    (void)hipMemsetAsync(CT, 0, 1048576 * sizeof(float), stream);
    // 8. conv attention, 2 batches per dispatch
    for (int p = 0; p < 2; ++p) {
        mfma_nt<128, 0, false><<<dim3(16, 2, 32), 256, 0, stream>>>(
            Qcb + (long)p * 524288, 262144L, 64L,
            Kcb + (long)p * 4194304, 2097152L, 64L,
            SCu, 8388608L, 524288L, nullptr, nullptr,
            64, 1024, 1024, 2048, 0.125f, 16, 1, MFMA_TAIL);
        softmax_gate_kernel<16><<<2048, 256, 0, stream>>>(
            SCu, GM + p * 512, GU + p * 4096, 12, 255, 256, 2048);
        mfma_nt<64, 2, false><<<dim3(1, 2, 256), 256, 0, stream>>>(
            SCu, 8388608L, 524288L,
            VTc + (long)p * 4194304, 2097152L, 131072L,
            (void*)(CT + (long)p * 524288), 262144L, 64L, nullptr, nullptr,
            2048, 2048, 2048, 1024, 1.0f, 16, 8, MFMA_TAIL);
    }
    // 9-10. conv out-proj + residual + r_conv_scalar -> o_macro_new
    cvt_kernel<<<1024, 256, 0, stream>>>(CT, CTb);
    mfma_nt<128, 3, false><<<dim3(8, 8, 1), 256, 0, stream>>>(
        CTb, 0L, 0L, WB + 6 * 1048576, 0L, 0L, out_macro, 0L, 0L, nullptr, nullptr,
        1024, 1024, 1024, 1024, 1.0f, 1, 1, o_macro, RCS, nullptr, nullptr, 0L, 0);
    // 11. emer attention, 2 batches per dispatch
    for (int p = 0; p < 2; ++p) {
        mfma_nt<128, 0, false><<<dim3(2, 16, 32), 256, 0, stream>>>(
            Qeb + (long)p * 4194304, 2097152L, 64L,
            Keb + (long)p * 524288, 262144L, 64L,
            SCu, 8388608L, 524288L, nullptr, nullptr,
            64, 1024, 1024, 256, 0.125f, 16, 1, MFMA_TAIL);
        softmax_gate_kernel<2><<<16384, 256, 0, stream>>>(
            SCu, GU + p * 4096, GM + p * 512, 15, 2047, 2048, 256);
        mfma_nt<64, 0, false><<<dim3(1, 16, 32), 256, 0, stream>>>(
            SCu, 8388608L, 524288L,
            VTe + (long)p * 524288, 262144L, 16384L,
            (void*)(CTe + (long)p * 4194304), 2097152L, 64L, nullptr, nullptr,
            256, 256, 256, 1024, 1.0f, 16, 1, MFMA_TAIL);
    }
    // 12. emer out-proj + residual + r_emer_scalar -> o_micro_new  (mfma8, 256x128)
    mfma8<128, 3><<<dim3(8, 32), 512, 0, stream>>>(
        CTe, WB + 7 * 1048576, out_micro, nullptr, nullptr,
        1024, 1024, 1024, o_micro, RES);
}

// Round 10
// 397.650 us; speedup vs baseline: 1.0086x; 1.0086x over previous
//
#include <hip/hip_runtime.h>
#include <math.h>

// B=4, TU=2048, TM=256, D=1024, H=16, DH=64, PAIRS=512
typedef unsigned short u16;
typedef __attribute__((ext_vector_type(8))) short bf16x8;
typedef __attribute__((ext_vector_type(4))) float f32x4;

__device__ __forceinline__ float sigmoidf_(float x) { return 1.0f / (1.0f + __expf(-x)); }
__device__ __forceinline__ u16 f2bf(float v) {
    union { float f; unsigned u; } x; x.f = v;
    unsigned r = x.u + 0x7fffu + ((x.u >> 16) & 1u);
    return (u16)(r >> 16);
}
__device__ __forceinline__ float bf2f(u16 u) {
    union { unsigned u; float f; } x; x.u = ((unsigned)u) << 16; return x.f;
}

#define GLD(src, dst) __builtin_amdgcn_global_load_lds( \
        (const __attribute__((address_space(1))) void*)(src), \
        (__attribute__((address_space(3))) void*)(dst), 16, 0, 0)

// ---------------------------------------------------------------------------
// balance_norm + gate + fused pairnorm, ONE WAVE PER ROW (shuffle-only).
// ---------------------------------------------------------------------------
__global__ void __launch_bounds__(256) norm_gate_kernel(
    const float* __restrict__ X,
    const float* __restrict__ w, const float* __restrict__ bvec,
    const float* __restrict__ bw_p,
    const float* __restrict__ gw, const float* __restrict__ gb_p,
    u16* __restrict__ OUT, u16* __restrict__ PN, float* __restrict__ G)
{
    const int row = blockIdx.x * 4 + (threadIdx.x >> 6);
    const int lane = threadIdx.x & 63;
    const float* xr = X + (size_t)row * 1024 + lane * 16;
    float4 xa = ((const float4*)xr)[0];
    float4 xb = ((const float4*)xr)[1];
    float4 xc = ((const float4*)xr)[2];
    float4 xd = ((const float4*)xr)[3];
    float s1 = (xa.x + xa.y + xa.z + xa.w) + (xb.x + xb.y + xb.z + xb.w)
             + (xc.x + xc.y + xc.z + xc.w) + (xd.x + xd.y + xd.z + xd.w);
    float s2 = xa.x * xa.x + xa.y * xa.y + xa.z * xa.z + xa.w * xa.w
             + xb.x * xb.x + xb.y * xb.y + xb.z * xb.z + xb.w * xb.w
             + xc.x * xc.x + xc.y * xc.y + xc.z * xc.z + xc.w * xc.w
             + xd.x * xd.x + xd.y * xd.y + xd.z * xd.z + xd.w * xd.w;
    #pragma unroll
    for (int o = 1; o <= 32; o <<= 1) s1 += __shfl_xor(s1, o);
    float h2 = s2;
    #pragma unroll
    for (int o = 1; o <= 16; o <<= 1) h2 += __shfl_xor(h2, o);
    const float oth = __shfl_xor(h2, 32);
    const float slo = (lane < 32) ? h2 : oth;
    const float shi = (lane < 32) ? oth : h2;
    const float mu = s1 * (1.0f / 1024.0f);
    const float var = (slo + shi) * (1.0f / 1024.0f) - mu * mu;
    const float rstd = rsqrtf(var + 1e-6f);
    const float imb = (slo - shi) * (1.0f / 512.0f) * (*bw_p);
    const float corr = (lane < 32) ? -imb : imb;
    const int i0 = lane * 16;
    const float4* wp = (const float4*)(w + i0);
    const float4* bp = (const float4*)(bvec + i0);
    const float4* gp = (const float4*)(gw + i0);
    float o16[16];
    float gd = 0.0f;
    #pragma unroll
    for (int q = 0; q < 4; ++q) {
        float4 xv = (q == 0) ? xa : (q == 1) ? xb : (q == 2) ? xc : xd;
        float4 wv = wp[q], bv = bp[q], gv = gp[q];
        float t0 = (xv.x - mu) * rstd * wv.x + bv.x + corr;
        float t1 = (xv.y - mu) * rstd * wv.y + bv.y + corr;
        float t2 = (xv.z - mu) * rstd * wv.z + bv.z + corr;
        float t3 = (xv.w - mu) * rstd * wv.w + bv.w + corr;
        gd += t0 * gv.x + t1 * gv.y + t2 * gv.z + t3 * gv.w;
        o16[4 * q + 0] = t0; o16[4 * q + 1] = t1; o16[4 * q + 2] = t2; o16[4 * q + 3] = t3;
    }
    #pragma unroll
    for (int o = 1; o <= 32; o <<= 1) gd += __shfl_xor(gd, o);
    if (lane == 0) G[row] = sigmoidf_(gd + *gb_p);
    u16 ob[16], pn[16];
    #pragma unroll
    for (int j = 0; j < 16; ++j) ob[j] = f2bf(o16[j]);
    #pragma unroll
    for (int j = 0; j < 8; ++j) {
        float px = o16[2 * j] + 1e-8f, py = o16[2 * j + 1] + 1e-8f;
        float rr = rsqrtf(px * px + py * py);
        pn[2 * j] = f2bf(px * rr); pn[2 * j + 1] = f2bf(py * rr);
    }
    *(uint4*)(OUT + (size_t)row * 1024 + i0) = *(uint4*)ob;
    *(uint4*)(OUT + (size_t)row * 1024 + i0 + 8) = *(uint4*)(ob + 8);
    *(uint4*)(PN + (size_t)row * 1024 + i0) = *(uint4*)pn;
    *(uint4*)(PN + (size_t)row * 1024 + i0 + 8) = *(uint4*)(pn + 8);
}

// ---------------------------------------------------------------------------
// weight fp32 -> bf16 (8 slots of 1M elements; order set by pointer args)
// ---------------------------------------------------------------------------
__global__ void __launch_bounds__(256) wconv_kernel(
    const float* w0, const float* w1, const float* w2, const float* w3,
    const float* w4, const float* w5, const float* w6, const float* w7,
    u16* __restrict__ dst)
{
    const float* s;
    switch (blockIdx.y) {
        case 0: s = w0; break; case 1: s = w1; break;
        case 2: s = w2; break; case 3: s = w3; break;
        case 4: s = w4; break; case 5: s = w5; break;
        case 6: s = w6; break; default: s = w7; break;
    }
    long i = (long)blockIdx.x * 1024 + threadIdx.x * 4;
    float4 v = *(const float4*)(s + i);
    u16 o[4] = { f2bf(v.x), f2bf(v.y), f2bf(v.z), f2bf(v.w) };
    *(uint2*)(dst + (long)blockIdx.y * 1048576 + i) = *(uint2*)o;
}

__global__ void __launch_bounds__(256) cvt_kernel(const float* __restrict__ S, u16* __restrict__ D)
{
    long i = ((long)blockIdx.x * 256 + threadIdx.x) * 4;
    float4 v = *(const float4*)(S + i);
    u16 o[4] = { f2bf(v.x), f2bf(v.y), f2bf(v.z), f2bf(v.w) };
    *(uint2*)(D + i) = *(uint2*)o;
}

// ---------------------------------------------------------------------------
// mfma8: 256xBN-tile bf16 NT GEMM, BK=32, 512 threads = 8 waves (2M x 4N).
// TWO-SUB-PHASE K-step (m201 pattern on fragment-order LDS, ring-3, T4):
//  phase A: ds_read B0..NR-1 + A0..3 ; GLD A-half(i+2) ; bar ; lgkm0 ;
//           setprio1 ; MFMA m0..3 ; setprio0 ; bar
//  phase B: ds_read A4..7 ; GLD B-half(i+2) ; bar ; lgkm0 ;
//           setprio1 ; MFMA m4..7 ; setprio0 ; vmcnt(counted) ; bar
// Counted vmcnt once per K-step; staging never drains in steady state.
// EPI 3: f32 base[idx]+acc*rs[row]
// EPI 6: micro fused 3-way sections (Kc bf16 | VTc transposed uint2 | Qe bf16)
// ---------------------------------------------------------------------------
template<int BN, int EPI>
__global__ void __launch_bounds__(512, (BN == 128) ? 4 : 1) mfma8(
    const u16* __restrict__ A, const u16* __restrict__ B,
    void* __restrict__ C, void* __restrict__ Cx, void* __restrict__ Cy,
    int K, int lda, int ldb,
    const float* __restrict__ base, const float* __restrict__ rs)
{
    constexpr int NR = BN / 64;                 // N-frags per wave
    constexpr int RSTRIDE = 8192 + BN * 32;     // u16 per ring slot
    __shared__ __align__(16) u16 sh[3 * RSTRIDE];
    const int gx = gridDim.x, gy = gridDim.y;
    const int lin = blockIdx.x + gx * blockIdx.y;
    const int xcd = lin & 7, off = lin >> 3;
    const int lby = gy >> 3;
    const int by = xcd * lby + (off % lby);
    const int bx = off / lby;
    const int t = threadIdx.x;
    const int lane = t & 63, w = t >> 6;
    const int wm = w >> 2, wn = w & 3;
    const long m0 = (long)by * 256;
    const long n0 = (long)bx * BN;
    const int frow = lane & 15, fk = (lane >> 4) * 8;
    const u16* Ag0 = A + (m0 + w * 16 + frow) * lda + fk;
    const u16* Ag1 = Ag0 + 128L * lda;
    const u16* Bg0 = B + (n0 + w * 16 + frow) * ldb + fk;
    const u16* Bg1 = Bg0 + 128L * ldb;

    auto stageA = [&](int i, int r) {
        const int k0 = i << 5;
        u16* d = sh + r * RSTRIDE;
        GLD(Ag0 + k0, d + w * 512);
        GLD(Ag1 + k0, d + (8 + w) * 512);
    };
    auto stageB = [&](int i, int r) {
        const int k0 = i << 5;
        u16* d = sh + r * RSTRIDE;
        GLD(Bg0 + k0, d + 8192 + w * 512);
        if constexpr (BN == 256) GLD(Bg1 + k0, d + 8192 + (8 + w) * 512);
    };

    const int nIter = K >> 5;
    f32x4 acc[8][NR] = {};
    stageA(0, 0); stageB(0, 0);
    stageA(1, 1); stageB(1, 1);
    if constexpr (BN == 256) asm volatile("s_waitcnt vmcnt(4)" ::: "memory");
    else                     asm volatile("s_waitcnt vmcnt(3)" ::: "memory");
    __builtin_amdgcn_sched_barrier(0);
    __builtin_amdgcn_s_barrier();
    int r = 0;
    for (int i = 0; i < nIter; ++i) {
        const bool pre = (i + 2 < nIter);
        int r2 = r + 2; if (r2 >= 3) r2 -= 3;
        const u16* ra = sh + r * RSTRIDE;
        // ---------- phase A ----------
        bf16x8 bf[NR], af[4];
        #pragma unroll
        for (int ni = 0; ni < NR; ++ni)
            bf[ni] = *(const bf16x8*)(ra + 8192 + (wn * NR + ni) * 512 + lane * 8);
        #pragma unroll
        for (int mi = 0; mi < 4; ++mi)
            af[mi] = *(const bf16x8*)(ra + (wm * 8 + mi) * 512 + lane * 8);
        if (pre) stageA(i + 2, r2);
        __builtin_amdgcn_s_barrier();
        asm volatile("s_waitcnt lgkmcnt(0)" ::: "memory");
        __builtin_amdgcn_sched_barrier(0);
        __builtin_amdgcn_s_setprio(1);
        #pragma unroll
        for (int mi = 0; mi < 4; ++mi)
            #pragma unroll
            for (int ni = 0; ni < NR; ++ni)
                acc[mi][ni] = __builtin_amdgcn_mfma_f32_16x16x32_bf16(af[mi], bf[ni], acc[mi][ni], 0, 0, 0);
        __builtin_amdgcn_s_setprio(0);
        __builtin_amdgcn_sched_barrier(0);
        __builtin_amdgcn_s_barrier();
        // ---------- phase B ----------
        bf16x8 af2[4];
        #pragma unroll
        for (int mi = 0; mi < 4; ++mi)
            af2[mi] = *(const bf16x8*)(ra + (wm * 8 + 4 + mi) * 512 + lane * 8);
        if (pre) stageB(i + 2, r2);
        __builtin_amdgcn_s_barrier();
        asm volatile("s_waitcnt lgkmcnt(0)" ::: "memory");
        __builtin_amdgcn_sched_barrier(0);
        __builtin_amdgcn_s_setprio(1);
        #pragma unroll
        for (int mi = 0; mi < 4; ++mi)
            #pragma unroll
            for (int ni = 0; ni < NR; ++ni)
                acc[4 + mi][ni] = __builtin_amdgcn_mfma_f32_16x16x32_bf16(af2[mi], bf[ni], acc[4 + mi][ni], 0, 0, 0);
        __builtin_amdgcn_s_setprio(0);
        __builtin_amdgcn_sched_barrier(0);
        if (i + 1 < nIter) {
            if (pre) {
                if constexpr (BN == 256) asm volatile("s_waitcnt vmcnt(4)" ::: "memory");
                else                     asm volatile("s_waitcnt vmcnt(3)" ::: "memory");
            } else {
                asm volatile("s_waitcnt vmcnt(0)" ::: "memory");
            }
            __builtin_amdgcn_sched_barrier(0);
            __builtin_amdgcn_s_barrier();
        }
        ++r; if (r >= 3) r = 0;
    }
    // ---- epilogue ----
    const int l15 = lane & 15, l4 = lane >> 4;
    #pragma unroll
    for (int mi = 0; mi < 8; ++mi) {
        #pragma unroll
        for (int ni = 0; ni < NR; ++ni) {
            const long grow0 = m0 + wm * 128 + mi * 16 + l4 * 4;
            const long gcol  = n0 + wn * (BN / 4) + ni * 16 + l15;
            if constexpr (EPI == 3) {
                #pragma unroll
                for (int j = 0; j < 4; ++j) {
                    const long idx = (grow0 + j) * 1024 + gcol;
                    ((float*)C)[idx] = base[idx] + acc[mi][ni][j] * rs[grow0 + j];
                }
            } else {  // EPI == 6
                const int sec = (int)(n0 >> 10);
                if (sec == 0) {
                    #pragma unroll
                    for (int j = 0; j < 4; ++j)
                        ((u16*)C)[(grow0 + j) * 1024 + gcol] = f2bf(acc[mi][ni][j]);   // K_conv
                } else if (sec == 1) {
                    const long col = gcol - 1024;
                    u16 pk[4] = { f2bf(acc[mi][ni][0]), f2bf(acc[mi][ni][1]),
                                  f2bf(acc[mi][ni][2]), f2bf(acc[mi][ni][3]) };
                    const long idx = (grow0 >> 11) * 2097152 + col * 2048 + (grow0 & 2047);
                    *(uint2*)&((u16*)Cx)[idx] = *(uint2*)pk;                            // VT_conv
                } else {
                    #pragma unroll
                    for (int j = 0; j < 4; ++j)
                        ((u16*)Cy)[(grow0 + j) * 1024 + (gcol - 2048)] = f2bf(acc[mi][ni][j]); // Q_emer
                }
            }
        }
    }
}

// ---------------------------------------------------------------------------
// bf16 NT MFMA GEMM, 128xBN tile, BK=32, 256 threads (2x2 waves).
// 3-STAGE LDS PIPELINE, 2 TILES IN FLIGHT. (unchanged)
// ---------------------------------------------------------------------------
template<int BN, int EPI, bool SWZ>
__global__ void __launch_bounds__(256) mfma_nt(
    const u16* __restrict__ A, long zAb, long zAh,
    const u16* __restrict__ B, long zBb, long zBh,
    void* __restrict__ C, long zCb, long zCh,
    void* __restrict__ Cx, void* __restrict__ Cy,
    int K, int lda, int ldb, int ldc, float alpha, int nH, int nsplit,
    const float* __restrict__ base, const float* __restrict__ rs,
    const float* __restrict__ accB, float* __restrict__ OT,
    long zOT, int ldt)
{
    constexpr int NR = BN / 32;
    constexpr int ABUF = 128 * 32;
    constexpr int BBUF = BN * 32;
    __shared__ __align__(16) u16 sh[3 * (ABUF + BBUF)];
    u16* const Ab0 = sh;
    u16* const Bb0 = sh + 3 * ABUF;
    int bx, by, bz;
    if constexpr (SWZ) {
        const int gx = gridDim.x, gy = gridDim.y;
        const int lin = blockIdx.x + gx * blockIdx.y;
        const int xcd = lin & 7, c = lin >> 3;
        const int LBY = gy >> 3;
        const int SPB = 4 * LBY;
        const int sc = c / SPB, rr = c - sc * SPB;
        const int byl = rr >> 2, bxl = rr & 3;
        by = xcd * LBY + byl;
        bx = sc * 4 + bxl;
        bz = 0;
    } else {
        bx = blockIdx.x; by = blockIdx.y; bz = blockIdx.z;
    }
    const int t = threadIdx.x;
    const int lane = t & 63, w = t >> 6;
    const int wr = w >> 1, wc = w & 1;
    const int slab = bz / nsplit, ks = bz - slab * nsplit;
    const int b = slab / nH, h = slab - b * nH;
    const int kchunk = K / nsplit;
    const int kbeg = ks * kchunk, kend = kbeg + kchunk;
    const long m0 = (long)by * 128;
    const long n0 = (long)bx * BN;
    const int frow = lane & 15, fko = (lane >> 4) * 8;
    const u16* gaA = A + zAb * b + zAh * h + (m0 + 32 * w + frow) * lda + fko;
    const u16* gbB;
    if constexpr (BN == 128) gbB = B + zBb * b + zBh * h + (n0 + 32 * w + frow) * ldb + fko;
    else                     gbB = B + zBb * b + zBh * h + (n0 + 16 * w + frow) * ldb + fko;

    auto stage = [&](int kk, int p) {
        u16* ap = Ab0 + p * ABUF;
        u16* bp = Bb0 + p * BBUF;
        GLD(gaA + kk, ap + 2 * w * 512);
        GLD(gaA + 16L * lda + kk, ap + (2 * w + 1) * 512);
        if constexpr (BN == 128) {
            GLD(gbB + kk, bp + 2 * w * 512);
            GLD(gbB + 16L * ldb + kk, bp + (2 * w + 1) * 512);
        } else {
            GLD(gbB + kk, bp + w * 512);
        }
    };

    const int nIter = (kend - kbeg) >> 5;
    f32x4 acc[4][NR] = {};
    stage(kbeg, 0);
    if (nIter > 1) stage(kbeg + 32, 1);
    int cur = 0;
    for (int i = 0; i < nIter; ++i) {
        if (i + 2 < nIter) {
            int p2 = cur + 2; if (p2 >= 3) p2 -= 3;
            stage(kbeg + (i + 2) * 32, p2);
            if constexpr (BN == 128) asm volatile("s_waitcnt vmcnt(8)" ::: "memory");
            else                     asm volatile("s_waitcnt vmcnt(6)" ::: "memory");
        } else if (i + 1 < nIter) {
            if constexpr (BN == 128) asm volatile("s_waitcnt vmcnt(4)" ::: "memory");
            else                     asm volatile("s_waitcnt vmcnt(3)" ::: "memory");
        } else {
            asm volatile("s_waitcnt vmcnt(0)" ::: "memory");
        }
        __builtin_amdgcn_sched_barrier(0);
        __builtin_amdgcn_s_barrier();
        __builtin_amdgcn_sched_barrier(0);
        const u16* ap = Ab0 + cur * ABUF;
        const u16* bp = Bb0 + cur * BBUF;
        bf16x8 af[4], bfr[NR];
        #pragma unroll
        for (int m = 0; m < 4; ++m)
            af[m] = *(const bf16x8*)(ap + (wr * 4 + m) * 512 + lane * 8);
        #pragma unroll
        for (int n = 0; n < NR; ++n)
            bfr[n] = *(const bf16x8*)(bp + (wc * NR + n) * 512 + lane * 8);
        asm volatile("s_waitcnt lgkmcnt(0)" ::: "memory");
        __builtin_amdgcn_sched_barrier(0);
        __builtin_amdgcn_s_barrier();
        #pragma unroll
        for (int m = 0; m < 4; ++m)
            #pragma unroll
            for (int n = 0; n < NR; ++n)
                acc[m][n] = __builtin_amdgcn_mfma_f32_16x16x32_bf16(af[m], bfr[n], acc[m][n], 0, 0, 0);
        cur = (cur == 2) ? 0 : cur + 1;
    }
    const long Coff = zCb * b + zCh * h;
    const int l15 = lane & 15, l4 = lane >> 4;
    if constexpr (EPI == 6 || EPI == 7) {
        constexpr int VTSEC = (EPI == 6) ? 1 : 2;
        if ((int)(n0 >> 10) == VTSEC) {
            __syncthreads();
            #pragma unroll
            for (int m = 0; m < 4; ++m)
                #pragma unroll
                for (int n = 0; n < NR; ++n)
                    #pragma unroll
                    for (int j = 0; j < 4; ++j)
                        sh[(wc * 64 + n * 16 + l15) * 136 + (wr * 64 + m * 16 + l4 * 4 + j)]
                            = f2bf(acc[m][n][j] * alpha);
            __syncthreads();
            constexpr int  LT   = (EPI == 6) ? 2048 : 256;
            constexpr int  L2T  = (EPI == 6) ? 11 : 8;
            constexpr long BSTR = (EPI == 6) ? 2097152L : 262144L;
            u16* dst = (EPI == 6) ? (u16*)Cx : (u16*)Cy;
            const long bb  = m0 >> L2T;
            const int  tt0 = (int)(m0 & (LT - 1));
            const long colb = n0 & 1023;
            #pragma unroll
            for (int it = 0; it < 8; ++it) {
                const int c = it * 16 + (t >> 4);
                const int rr = (t & 15) * 8;
                uint4 v = *(const uint4*)&sh[c * 136 + rr];
                *(uint4*)&dst[bb * BSTR + (colb + c) * LT + tt0 + rr] = v;
            }
            return;
        }
    }
    #pragma unroll
    for (int m = 0; m < 4; ++m) {
        #pragma unroll
        for (int n = 0; n < NR; ++n) {
            #pragma unroll
            for (int j = 0; j < 4; ++j) {
                const long grow = m0 + wr * 64 + m * 16 + l4 * 4 + j;
                const long gcol = n0 + wc * (BN / 2) + n * 16 + l15;
                const float v = acc[m][n][j] * alpha;
                if constexpr (EPI == 0) {
                    ((u16*)C)[Coff + grow * ldc + gcol] = f2bf(v);
                } else if constexpr (EPI == 2) {
                    atomicAdd((float*)C + Coff + grow * ldc + gcol, v);
                } else if constexpr (EPI == 3) {
                    const long idx = grow * ldc + gcol;
                    ((float*)C)[idx] = base[idx] + v * rs[grow];
                } else if constexpr (EPI == 5) {
                    const long idx = Coff + grow * ldc + gcol;
                    ((float*)C)[idx] = 0.7f * base[idx] + 0.3f * v;
                    const long tidx = zOT * b + gcol * (long)ldt + grow;
                    OT[tidx] = 0.7f * accB[tidx] + 0.3f * v;
                } else if constexpr (EPI == 6) {
                    if (n0 < 1024) ((u16*)C)[grow * 1024 + gcol] = f2bf(v);
                    else           ((u16*)Cy)[grow * 1024 + (gcol - 2048)] = f2bf(v);
                } else {  // EPI == 7
                    if (n0 < 1024) ((u16*)C)[grow * 1024 + gcol] = f2bf(v);
                    else           ((u16*)Cx)[grow * 1024 + (gcol - 1024)] = f2bf(v);
                }
            }
        }
    }
}

// ---------------------------------------------------------------------------
// softmax + gate + renorm, IN PLACE on bf16 scores; one wave per row.
// ---------------------------------------------------------------------------
template<int NU2>
__global__ void __launch_bounds__(256) softmax_gate_kernel(
    u16* __restrict__ P,
    const float* __restrict__ AG, const float* __restrict__ EG,
    int bshift, int qmask, int qld, int egld)
{
    const int row = blockIdx.x * 4 + (threadIdx.x >> 6);
    const int lane = threadIdx.x & 63;
    const int bl = row >> bshift;
    unsigned* pr = (unsigned*)(P + (long)row * (NU2 * 128));
    const float* egr = EG + (long)bl * egld;
    float r0[NU2], r1[NU2];
    float m = -3.4e38f;
    #pragma unroll
    for (int u = 0; u < NU2; ++u) {
        unsigned v = pr[lane + 64 * u];
        r0[u] = bf2f((u16)(v & 0xffffu));
        r1[u] = bf2f((u16)(v >> 16));
        m = fmaxf(m, fmaxf(r0[u], r1[u]));
    }
    for (int o = 32; o > 0; o >>= 1) m = fmaxf(m, __shfl_xor(m, o));
    float l = 0.0f, se = 0.0f;
    #pragma unroll
    for (int u = 0; u < NU2; ++u) {
        float e0 = __expf(r0[u] - m), e1 = __expf(r1[u] - m);
        l += e0 + e1;
        float2 eg = *(const float2*)(egr + 2 * (lane + 64 * u));
        r0[u] = e0 * eg.x; r1[u] = e1 * eg.y;
        se += r0[u] + r1[u];
    }
    for (int o = 32; o > 0; o >>= 1) { l += __shfl_xor(l, o); se += __shfl_xor(se, o); }
    const float ag = AG[(long)bl * qld + (row & qmask)];
    const float f = ag / (ag * se + l * 1e-8f);
    #pragma unroll
    for (int u = 0; u < NU2; ++u) {
        unsigned vo = (unsigned)f2bf(r0[u] * f) | ((unsigned)f2bf(r1[u] * f) << 16);
        pr[lane + 64 * u] = vo;
    }
}

__global__ void __launch_bounds__(256) rowmean_sig_kernel(
    const float* __restrict__ X, int len, float invlen,
    const float* __restrict__ alpha_p, float* __restrict__ OUT)
{
    const int row = blockIdx.x * 4 + (threadIdx.x >> 6);
    const int lane = threadIdx.x & 63;
    const float* xr = X + (long)row * len;
    float s = 0.0f;
    for (int k = lane; k < len; k += 64) s += xr[k];
    for (int o = 32; o > 0; o >>= 1) s += __shfl_xor(s, o);
    if (lane == 0) OUT[row] = sigmoidf_((*alpha_p) * s * invlen);
}

#define MFMA_TAIL nullptr, nullptr, nullptr, nullptr, 0L, 0

extern "C" void kernel_launch(void* const* d_in, const int* in_sizes, int n_in,
                              void* d_out, int out_size, void* d_ws, size_t ws_size,
                              hipStream_t stream)
{
    (void)in_sizes; (void)n_in; (void)out_size; (void)ws_size;
    const float* o_micro    = (const float*)d_in[0];
    const float* o_macro    = (const float*)d_in[1];
    const float* r_conv_acc = (const float*)d_in[2];
    const float* r_emer_acc = (const float*)d_in[3];
    const float* ln_u_w = (const float*)d_in[4];
    const float* ln_u_b = (const float*)d_in[5];
    const float* bw_u   = (const float*)d_in[6];
    const float* ln_m_w = (const float*)d_in[7];
    const float* ln_m_b = (const float*)d_in[8];
    const float* bw_m   = (const float*)d_in[9];
    const float* gu_w   = (const float*)d_in[10];
    const float* gu_b   = (const float*)d_in[11];
    const float* gm_w   = (const float*)d_in[12];
    const float* gm_b   = (const float*)d_in[13];
    const float* wq_c   = (const float*)d_in[14];
    const float* wk_c   = (const float*)d_in[15];
    const float* wv_c   = (const float*)d_in[16];
    const float* wo_c   = (const float*)d_in[17];
    const float* wq_e   = (const float*)d_in[18];
    const float* wk_e   = (const float*)d_in[19];
    const float* wv_e   = (const float*)d_in[20];
    const float* wo_e   = (const float*)d_in[21];
    const float* res_alpha = (const float*)d_in[22];

    float* out = (float*)d_out;
    float* out_micro = out;              // (4,2048,1024)
    float* out_macro = out + 8388608;    // (4,256,1024)
    float* out_rconv = out + 9437184;    // (4,256,2048)
    float* out_remer = out + 11534336;   // (4,2048,256)

    // workspace (f32 slot offsets; bf16 buffers use 2 el/slot)
    float* ws = (float*)d_ws;
    u16* OUb = (u16*)ws;                       // 8388608 bf16 (normed micro)
    u16* OMb = (u16*)(ws + 4194304);           // 1048576 bf16 (normed macro)
    u16* WB  = (u16*)(ws + 4718592);           // 8 x 1048576 bf16 weights
                                               //   [wk_c wv_c wq_e | wq_c wk_e wv_e | wo_c wo_e]
    u16* Kcb = (u16*)(ws + 8912896);           // conv K (8192x1024) -> later CTe
    u16* VTc = (u16*)(ws + 13107200);          // conv V^T [b][h][64][2048]
    u16* Qeb = (u16*)(ws + 17301504);          // emer Q (8192x1024)
    u16* Qcb = (u16*)(ws + 21495808);          // conv Q (1024x1024) -> later CTb
    u16* Keb = (u16*)(ws + 22020096);          // emer K (1024x1024)
    u16* VTe = (u16*)(ws + 22544384);          // emer V^T [b][h][64][256]
    u16* PNu = (u16*)(ws + 23068672);          // pairnormed micro (8.4M bf16)
    float* CT = ws + 27262976;                 // conv ctx f32 (4x256x1024); early: PNm
    float* GU = ws + 28311552;                 // 8192
    float* GM = GU + 8192;                     // 1024
    float* RCS = GM + 1024;                    // 1024
    float* RES = RCS + 1024;                   // 8192
    u16* PNm = (u16*)CT;
    u16* CTb = Qcb;
    u16* CTe = Kcb;
    u16* SCu = (u16*)out_micro;                // 2-batch bf16 score/prob slab (16.8M els)

    // 1. weights -> bf16, reordered for fused projections
    wconv_kernel<<<dim3(1024, 8), 256, 0, stream>>>(wk_c, wv_c, wq_e, wq_c, wk_e, wv_e, wo_c, wo_e, WB);
    // 2. balance norms + gates + fused pairnorm (wave-per-row)
    norm_gate_kernel<<<2048, 256, 0, stream>>>(o_micro, ln_u_w, ln_u_b, bw_u, gu_w, gu_b, OUb, PNu, GU);
    norm_gate_kernel<<<256, 256, 0, stream>>>(o_macro, ln_m_w, ln_m_b, bw_m, gm_w, gm_b, OMb, PNm, GM);
    // 3. resonance GEMM + 0.7/0.3 blend + transposed write
    mfma_nt<128, 5, false><<<dim3(16, 2, 4), 256, 0, stream>>>(
        PNm, 262144L, 0L, PNu, 2097152L, 0L, out_rconv, 524288L, 0L, nullptr, nullptr,
        1024, 1024, 1024, 2048, 1.0f / 512.0f, 1, 1,
        r_conv_acc, nullptr, r_emer_acc, out_remer, 524288L, 256);
    // 4. resonance scalars
    rowmean_sig_kernel<<<256, 256, 0, stream>>>(out_rconv, 2048, 1.0f / 2048.0f, res_alpha, RCS);
    rowmean_sig_kernel<<<2048, 256, 0, stream>>>(out_remer, 256, 1.0f / 256.0f, res_alpha, RES);
    // 5. fused micro-side projections: [K_conv | VT_conv | Q_emer]  (mfma8 256x256, 2-sub-phase)
    mfma8<256, 6><<<dim3(12, 32), 512, 0, stream>>>(
        OUb, WB, Kcb, VTc, Qeb, 1024, 1024, 1024, nullptr, nullptr);
    // 6. fused macro-side projections: [Q_conv | K_emer | VT_emer]
    mfma_nt<128, 7, true><<<dim3(24, 8, 1), 256, 0, stream>>>(
        OMb, 0L, 0L, WB + 3 * 1048576, 0L, 0L, Qcb, 0L, 0L, Keb, VTe,
        1024, 1024, 1024, 1024, 1.0f, 1, 1, MFMA_TAIL);
    // 7. conv ctx accumulator
    (void)hipMemsetAsync(CT, 0, 1048576 * sizeof(float), stream);
    // 8. conv attention, 2 batches per dispatch
    for (int p = 0; p < 2; ++p) {
        mfma_nt<128, 0, false><<<dim3(16, 2, 32), 256, 0, stream>>>(
            Qcb + (long)p * 524288, 262144L, 64L,
            Kcb + (long)p * 4194304, 2097152L, 64L,
            SCu, 8388608L, 524288L, nullptr, nullptr,
            64, 1024, 1024, 2048, 0.125f, 16, 1, MFMA_TAIL);
        softmax_gate_kernel<16><<<2048, 256, 0, stream>>>(
            SCu, GM + p * 512, GU + p * 4096, 12, 255, 256, 2048);
        mfma_nt<64, 2, false><<<dim3(1, 2, 256), 256, 0, stream>>>(
            SCu, 8388608L, 524288L,
            VTc + (long)p * 4194304, 2097152L, 131072L,
            (void*)(CT + (long)p * 524288), 262144L, 64L, nullptr, nullptr,
            2048, 2048, 2048, 1024, 1.0f, 16, 8, MFMA_TAIL);
    }
    // 9-10. conv out-proj + residual + r_conv_scalar -> o_macro_new
    cvt_kernel<<<1024, 256, 0, stream>>>(CT, CTb);
    mfma_nt<128, 3, false><<<dim3(8, 8, 1), 256, 0, stream>>>(
        CTb, 0L, 0L, WB + 6 * 1048576, 0L, 0L, out_macro, 0L, 0L, nullptr, nullptr,
        1024, 1024, 1024, 1024, 1.0f, 1, 1, o_macro, RCS, nullptr, nullptr, 0L, 0);
    // 11. emer attention, 2 batches per dispatch
    for (int p = 0; p < 2; ++p) {
        mfma_nt<128, 0, false><<<dim3(2, 16, 32), 256, 0, stream>>>(
            Qeb + (long)p * 4194304, 2097152L, 64L,
            Keb + (long)p * 524288, 262144L, 64L,
            SCu, 8388608L, 524288L, nullptr, nullptr,
            64, 1024, 1024, 256, 0.125f, 16, 1, MFMA_TAIL);
        softmax_gate_kernel<2><<<16384, 256, 0, stream>>>(
            SCu, GU + p * 4096, GM + p * 512, 15, 2047, 2048, 256);
        mfma_nt<64, 0, false><<<dim3(1, 16, 32), 256, 0, stream>>>(
            SCu, 8388608L, 524288L,
            VTe + (long)p * 524288, 262144L, 16384L,
            (void*)(CTe + (long)p * 4194304), 2097152L, 64L, nullptr, nullptr,
            256, 256, 256, 1024, 1.0f, 16, 1, MFMA_TAIL);
    }
    // 12. emer out-proj + residual + r_emer_scalar -> o_micro_new  (mfma8 256x128, 2-sub-phase)
    mfma8<128, 3><<<dim3(8, 32), 512, 0, stream>>>(
        CTe, WB + 7 * 1048576, out_micro, nullptr, nullptr,
        1024, 1024, 1024, o_micro, RES);
}

// Round 11
// 297.335 us; speedup vs baseline: 1.3489x; 1.3374x over previous
//
#include <hip/hip_runtime.h>
#include <math.h>

// B=4, TU=2048, TM=256, D=1024, H=16, DH=64, PAIRS=512
typedef unsigned short u16;
typedef __attribute__((ext_vector_type(8))) short bf16x8;
typedef __attribute__((ext_vector_type(4))) float f32x4;

__device__ __forceinline__ float sigmoidf_(float x) { return 1.0f / (1.0f + __expf(-x)); }
__device__ __forceinline__ u16 f2bf(float v) {
    union { float f; unsigned u; } x; x.f = v;
    unsigned r = x.u + 0x7fffu + ((x.u >> 16) & 1u);
    return (u16)(r >> 16);
}
__device__ __forceinline__ float bf2f(u16 u) {
    union { unsigned u; float f; } x; x.u = ((unsigned)u) << 16; return x.f;
}

#define GLD(src, dst) __builtin_amdgcn_global_load_lds( \
        (const __attribute__((address_space(1))) void*)(src), \
        (__attribute__((address_space(3))) void*)(dst), 16, 0, 0)
#define GLD4(src, dst) __builtin_amdgcn_global_load_lds( \
        (const __attribute__((address_space(1))) void*)(src), \
        (__attribute__((address_space(3))) void*)(dst), 4, 0, 0)

// ---------------------------------------------------------------------------
// balance_norm + gate + fused pairnorm, ONE WAVE PER ROW (shuffle-only).
// ---------------------------------------------------------------------------
__global__ void __launch_bounds__(256) norm_gate_kernel(
    const float* __restrict__ X,
    const float* __restrict__ w, const float* __restrict__ bvec,
    const float* __restrict__ bw_p,
    const float* __restrict__ gw, const float* __restrict__ gb_p,
    u16* __restrict__ OUT, u16* __restrict__ PN, float* __restrict__ G)
{
    const int row = blockIdx.x * 4 + (threadIdx.x >> 6);
    const int lane = threadIdx.x & 63;
    const float* xr = X + (size_t)row * 1024 + lane * 16;
    float4 xa = ((const float4*)xr)[0];
    float4 xb = ((const float4*)xr)[1];
    float4 xc = ((const float4*)xr)[2];
    float4 xd = ((const float4*)xr)[3];
    float s1 = (xa.x + xa.y + xa.z + xa.w) + (xb.x + xb.y + xb.z + xb.w)
             + (xc.x + xc.y + xc.z + xc.w) + (xd.x + xd.y + xd.z + xd.w);
    float s2 = xa.x * xa.x + xa.y * xa.y + xa.z * xa.z + xa.w * xa.w
             + xb.x * xb.x + xb.y * xb.y + xb.z * xb.z + xb.w * xb.w
             + xc.x * xc.x + xc.y * xc.y + xc.z * xc.z + xc.w * xc.w
             + xd.x * xd.x + xd.y * xd.y + xd.z * xd.z + xd.w * xd.w;
    #pragma unroll
    for (int o = 1; o <= 32; o <<= 1) s1 += __shfl_xor(s1, o);
    float h2 = s2;
    #pragma unroll
    for (int o = 1; o <= 16; o <<= 1) h2 += __shfl_xor(h2, o);
    const float oth = __shfl_xor(h2, 32);
    const float slo = (lane < 32) ? h2 : oth;
    const float shi = (lane < 32) ? oth : h2;
    const float mu = s1 * (1.0f / 1024.0f);
    const float var = (slo + shi) * (1.0f / 1024.0f) - mu * mu;
    const float rstd = rsqrtf(var + 1e-6f);
    const float imb = (slo - shi) * (1.0f / 512.0f) * (*bw_p);
    const float corr = (lane < 32) ? -imb : imb;
    const int i0 = lane * 16;
    const float4* wp = (const float4*)(w + i0);
    const float4* bp = (const float4*)(bvec + i0);
    const float4* gp = (const float4*)(gw + i0);
    float o16[16];
    float gd = 0.0f;
    #pragma unroll
    for (int q = 0; q < 4; ++q) {
        float4 xv = (q == 0) ? xa : (q == 1) ? xb : (q == 2) ? xc : xd;
        float4 wv = wp[q], bv = bp[q], gv = gp[q];
        float t0 = (xv.x - mu) * rstd * wv.x + bv.x + corr;
        float t1 = (xv.y - mu) * rstd * wv.y + bv.y + corr;
        float t2 = (xv.z - mu) * rstd * wv.z + bv.z + corr;
        float t3 = (xv.w - mu) * rstd * wv.w + bv.w + corr;
        gd += t0 * gv.x + t1 * gv.y + t2 * gv.z + t3 * gv.w;
        o16[4 * q + 0] = t0; o16[4 * q + 1] = t1; o16[4 * q + 2] = t2; o16[4 * q + 3] = t3;
    }
    #pragma unroll
    for (int o = 1; o <= 32; o <<= 1) gd += __shfl_xor(gd, o);
    if (lane == 0) G[row] = sigmoidf_(gd + *gb_p);
    u16 ob[16], pn[16];
    #pragma unroll
    for (int j = 0; j < 16; ++j) ob[j] = f2bf(o16[j]);
    #pragma unroll
    for (int j = 0; j < 8; ++j) {
        float px = o16[2 * j] + 1e-8f, py = o16[2 * j + 1] + 1e-8f;
        float rr = rsqrtf(px * px + py * py);
        pn[2 * j] = f2bf(px * rr); pn[2 * j + 1] = f2bf(py * rr);
    }
    *(uint4*)(OUT + (size_t)row * 1024 + i0) = *(uint4*)ob;
    *(uint4*)(OUT + (size_t)row * 1024 + i0 + 8) = *(uint4*)(ob + 8);
    *(uint4*)(PN + (size_t)row * 1024 + i0) = *(uint4*)pn;
    *(uint4*)(PN + (size_t)row * 1024 + i0 + 8) = *(uint4*)(pn + 8);
}

// ---------------------------------------------------------------------------
// weight fp32 -> bf16 (8 slots of 1M elements; order set by pointer args)
// ---------------------------------------------------------------------------
__global__ void __launch_bounds__(256) wconv_kernel(
    const float* w0, const float* w1, const float* w2, const float* w3,
    const float* w4, const float* w5, const float* w6, const float* w7,
    u16* __restrict__ dst)
{
    const float* s;
    switch (blockIdx.y) {
        case 0: s = w0; break; case 1: s = w1; break;
        case 2: s = w2; break; case 3: s = w3; break;
        case 4: s = w4; break; case 5: s = w5; break;
        case 6: s = w6; break; default: s = w7; break;
    }
    long i = (long)blockIdx.x * 1024 + threadIdx.x * 4;
    float4 v = *(const float4*)(s + i);
    u16 o[4] = { f2bf(v.x), f2bf(v.y), f2bf(v.z), f2bf(v.w) };
    *(uint2*)(dst + (long)blockIdx.y * 1048576 + i) = *(uint2*)o;
}

// ---------------------------------------------------------------------------
// FUSED FLASH ATTENTION (gated, deferred-normalization).
// One kernel for both sides; grid (TQ/64, H=16, B=4); 256 thr = 4 waves,
// wave w owns 16 q-rows (q = qt*64 + w*16 + (lane&15)).
// Swapped QK^T: S^T = mfma(A=K, B=Q) -> per-q stats are LANE-LOCAL (q=l&15);
// reduce over kv needs only shfl_xor(16,32).
// Online: m,l=Σe, se=Σe*eg, O=Σ(e*eg)*V^T (ctx^T); final scale
// ag/(ag*se + l*1e-8)  [exact: shift-invariant, gating defers].
// P->B-frag via per-wave LDS scratch written directly in B-fragment order.
// K/V^T double-buffered via global_load_lds + counted vmcnt(5) + 2 barriers.
// Epilogue: LDS transpose -> coalesced 16B stores of ctx[b][q][h*64+d].
// ---------------------------------------------------------------------------
__global__ void __launch_bounds__(256) attn_flash(
    const u16* __restrict__ Q, const u16* __restrict__ K,
    const u16* __restrict__ VT, const float* __restrict__ AG,
    const float* __restrict__ EG, u16* __restrict__ OC,
    int TQ, int TKV, long vbs)
{
    // u16 layout: Kbuf[2][4096] | Vbuf 8192+buf*4096 | Pbuf 16384+w*1024 |
    // egf (float) at +20480: [2][4][64]
    __shared__ __align__(16) u16 shm[21504];
    float* egf = (float*)(shm + 20480);
    const int t = threadIdx.x;
    const int lane = t & 63, w = t >> 6;
    const int l15 = lane & 15, g = lane >> 4;
    const int qt = blockIdx.x, h = blockIdx.y, b = blockIdx.z;
    const long qrow = (long)b * TQ + qt * 64 + w * 16 + l15;
    const u16* Qp = Q + qrow * 1024 + h * 64 + g * 8;
    const bf16x8 qf0 = *(const bf16x8*)(Qp);
    const bf16x8 qf1 = *(const bf16x8*)(Qp + 32);
    const u16* Kp = K + ((long)b * TKV + w * 16 + l15) * 1024 + h * 64 + g * 8;
    const u16* Vp = VT + (long)b * vbs + (long)(h * 64 + w * 16 + l15) * TKV + g * 8;
    const float* egp = EG + (long)b * TKV + lane;

    auto stage = [&](int kvt, int buf) {
        GLD(Kp + (long)kvt * 1024,      shm + buf * 4096 + (w * 2 + 0) * 512);
        GLD(Kp + (long)kvt * 1024 + 32, shm + buf * 4096 + (w * 2 + 1) * 512);
        GLD(Vp + kvt,      shm + 8192 + buf * 4096 + (w * 2 + 0) * 512);
        GLD(Vp + kvt + 32, shm + 8192 + buf * 4096 + (w * 2 + 1) * 512);
        GLD4(egp + kvt, egf + (buf * 4 + w) * 64);
    };

    const int nT = TKV >> 6;
    f32x4 O[4] = {};
    float mrun = -3.0e38f, lrun = 0.0f, serun = 0.0f;
    stage(0, 0);
    for (int i = 0; i < nT; ++i) {
        const int buf = i & 1;
        if (i + 1 < nT) {
            stage((i + 1) << 6, buf ^ 1);
            asm volatile("s_waitcnt vmcnt(5)" ::: "memory");
        } else {
            asm volatile("s_waitcnt vmcnt(0)" ::: "memory");
        }
        __builtin_amdgcn_sched_barrier(0);
        __builtin_amdgcn_s_barrier();
        const u16* kb = shm + buf * 4096;
        const u16* vb = shm + 8192 + buf * 4096;
        // ---- QK^T -> S^T (m=kv, n=q) ----
        f32x4 sa[4] = {};
        #pragma unroll
        for (int kvf = 0; kvf < 4; ++kvf) {
            bf16x8 kf = *(const bf16x8*)(kb + (kvf * 2 + 0) * 512 + lane * 8);
            sa[kvf] = __builtin_amdgcn_mfma_f32_16x16x32_bf16(kf, qf0, sa[kvf], 0, 0, 0);
        }
        #pragma unroll
        for (int kvf = 0; kvf < 4; ++kvf) {
            bf16x8 kf = *(const bf16x8*)(kb + (kvf * 2 + 1) * 512 + lane * 8);
            sa[kvf] = __builtin_amdgcn_mfma_f32_16x16x32_bf16(kf, qf1, sa[kvf], 0, 0, 0);
        }
        // ---- online softmax (per-q lane-local) ----
        float ev[4][4];
        float tmax = -3.0e38f;
        #pragma unroll
        for (int kvf = 0; kvf < 4; ++kvf)
            #pragma unroll
            for (int j = 0; j < 4; ++j) {
                float s = sa[kvf][j] * 0.125f;
                ev[kvf][j] = s;
                tmax = fmaxf(tmax, s);
            }
        tmax = fmaxf(tmax, __shfl_xor(tmax, 16));
        tmax = fmaxf(tmax, __shfl_xor(tmax, 32));
        const float mnew = fmaxf(mrun, tmax);
        const float corr = __expf(mrun - mnew);
        mrun = mnew;
        float suml = 0.0f, sumg = 0.0f;
        unsigned pk[4][2];
        #pragma unroll
        for (int kvf = 0; kvf < 4; ++kvf) {
            float4 eg4 = *(const float4*)(egf + (buf * 4 + w) * 64 + kvf * 16 + 4 * g);
            float e0 = __expf(ev[kvf][0] - mnew);
            float e1 = __expf(ev[kvf][1] - mnew);
            float e2 = __expf(ev[kvf][2] - mnew);
            float e3 = __expf(ev[kvf][3] - mnew);
            suml += (e0 + e1) + (e2 + e3);
            float g0 = e0 * eg4.x, g1 = e1 * eg4.y, g2 = e2 * eg4.z, g3 = e3 * eg4.w;
            sumg += (g0 + g1) + (g2 + g3);
            pk[kvf][0] = (unsigned)f2bf(g0) | ((unsigned)f2bf(g1) << 16);
            pk[kvf][1] = (unsigned)f2bf(g2) | ((unsigned)f2bf(g3) << 16);
        }
        suml += __shfl_xor(suml, 16); suml += __shfl_xor(suml, 32);
        sumg += __shfl_xor(sumg, 16); sumg += __shfl_xor(sumg, 32);
        lrun = lrun * corr + suml;
        serun = serun * corr + sumg;
        #pragma unroll
        for (int fd = 0; fd < 4; ++fd)
            #pragma unroll
            for (int j = 0; j < 4; ++j) O[fd][j] *= corr;
        // ---- P (S^T C-frags) -> per-wave LDS scratch in B-frag order ----
        // element (q=l15, kv=16kvf+4g+j): reader lane = q+16*(2(kvf&1)+(g>>1)),
        // slot i = 4(g&1)+j, chunk ksv = kvf>>1.
        u16* pw = shm + 16384 + w * 1024;
        #pragma unroll
        for (int kvf = 0; kvf < 4; ++kvf) {
            const int base = (kvf >> 1) * 512
                           + (l15 + 16 * (2 * (kvf & 1) + (g >> 1))) * 8
                           + 4 * (g & 1);
            *(unsigned*)(pw + base) = pk[kvf][0];
            *(unsigned*)(pw + base + 2) = pk[kvf][1];
        }
        // ---- PV: O[m=d][n=q] += mfma(A=V^T, B=P^T) ----
        #pragma unroll
        for (int ksv = 0; ksv < 2; ++ksv) {
            bf16x8 pf = *(const bf16x8*)(pw + ksv * 512 + lane * 8);
            #pragma unroll
            for (int fd = 0; fd < 4; ++fd) {
                bf16x8 vf = *(const bf16x8*)(vb + (fd * 2 + ksv) * 512 + lane * 8);
                O[fd] = __builtin_amdgcn_mfma_f32_16x16x32_bf16(vf, pf, O[fd], 0, 0, 0);
            }
        }
        if (i + 1 < nT) __builtin_amdgcn_s_barrier();
    }
    // ---- epilogue: scale, LDS transpose, coalesced store ----
    const float agv = AG[qrow];
    const float fac = agv / (agv * serun + lrun * 1e-8f);
    __syncthreads();
    u16* tw = shm + w * 1152;            // 16 q x 72 d (pad 8)
    #pragma unroll
    for (int fd = 0; fd < 4; ++fd) {
        const int d0 = fd * 16 + 4 * g;
        unsigned v01 = (unsigned)f2bf(O[fd][0] * fac) | ((unsigned)f2bf(O[fd][1] * fac) << 16);
        unsigned v23 = (unsigned)f2bf(O[fd][2] * fac) | ((unsigned)f2bf(O[fd][3] * fac) << 16);
        *(unsigned*)(tw + l15 * 72 + d0) = v01;
        *(unsigned*)(tw + l15 * 72 + d0 + 2) = v23;
    }
    const int qr = lane >> 2, part = lane & 3;
    uint4 va = *(const uint4*)(tw + qr * 72 + part * 16);
    uint4 vb2 = *(const uint4*)(tw + qr * 72 + part * 16 + 8);
    u16* op = OC + ((long)b * TQ + qt * 64 + w * 16 + qr) * 1024 + h * 64 + part * 16;
    *(uint4*)(op) = va;
    *(uint4*)(op + 8) = vb2;
}

// ---------------------------------------------------------------------------
// mfma8: 256xBN-tile bf16 NT GEMM, BK=32, 512 threads = 8 waves (2M x 4N).
// (unchanged from round 10 — two-sub-phase ring-3 counted-vmcnt)
// ---------------------------------------------------------------------------
template<int BN, int EPI>
__global__ void __launch_bounds__(512, (BN == 128) ? 4 : 1) mfma8(
    const u16* __restrict__ A, const u16* __restrict__ B,
    void* __restrict__ C, void* __restrict__ Cx, void* __restrict__ Cy,
    int K, int lda, int ldb,
    const float* __restrict__ base, const float* __restrict__ rs)
{
    constexpr int NR = BN / 64;
    constexpr int RSTRIDE = 8192 + BN * 32;
    __shared__ __align__(16) u16 sh[3 * RSTRIDE];
    const int gx = gridDim.x, gy = gridDim.y;
    const int lin = blockIdx.x + gx * blockIdx.y;
    const int xcd = lin & 7, off = lin >> 3;
    const int lby = gy >> 3;
    const int by = xcd * lby + (off % lby);
    const int bx = off / lby;
    const int t = threadIdx.x;
    const int lane = t & 63, w = t >> 6;
    const int wm = w >> 2, wn = w & 3;
    const long m0 = (long)by * 256;
    const long n0 = (long)bx * BN;
    const int frow = lane & 15, fk = (lane >> 4) * 8;
    const u16* Ag0 = A + (m0 + w * 16 + frow) * lda + fk;
    const u16* Ag1 = Ag0 + 128L * lda;
    const u16* Bg0 = B + (n0 + w * 16 + frow) * ldb + fk;
    const u16* Bg1 = Bg0 + 128L * ldb;

    auto stageA = [&](int i, int r) {
        const int k0 = i << 5;
        u16* d = sh + r * RSTRIDE;
        GLD(Ag0 + k0, d + w * 512);
        GLD(Ag1 + k0, d + (8 + w) * 512);
    };
    auto stageB = [&](int i, int r) {
        const int k0 = i << 5;
        u16* d = sh + r * RSTRIDE;
        GLD(Bg0 + k0, d + 8192 + w * 512);
        if constexpr (BN == 256) GLD(Bg1 + k0, d + 8192 + (8 + w) * 512);
    };

    const int nIter = K >> 5;
    f32x4 acc[8][NR] = {};
    stageA(0, 0); stageB(0, 0);
    stageA(1, 1); stageB(1, 1);
    if constexpr (BN == 256) asm volatile("s_waitcnt vmcnt(4)" ::: "memory");
    else                     asm volatile("s_waitcnt vmcnt(3)" ::: "memory");
    __builtin_amdgcn_sched_barrier(0);
    __builtin_amdgcn_s_barrier();
    int r = 0;
    for (int i = 0; i < nIter; ++i) {
        const bool pre = (i + 2 < nIter);
        int r2 = r + 2; if (r2 >= 3) r2 -= 3;
        const u16* ra = sh + r * RSTRIDE;
        bf16x8 bf[NR], af[4];
        #pragma unroll
        for (int ni = 0; ni < NR; ++ni)
            bf[ni] = *(const bf16x8*)(ra + 8192 + (wn * NR + ni) * 512 + lane * 8);
        #pragma unroll
        for (int mi = 0; mi < 4; ++mi)
            af[mi] = *(const bf16x8*)(ra + (wm * 8 + mi) * 512 + lane * 8);
        if (pre) stageA(i + 2, r2);
        __builtin_amdgcn_s_barrier();
        asm volatile("s_waitcnt lgkmcnt(0)" ::: "memory");
        __builtin_amdgcn_sched_barrier(0);
        __builtin_amdgcn_s_setprio(1);
        #pragma unroll
        for (int mi = 0; mi < 4; ++mi)
            #pragma unroll
            for (int ni = 0; ni < NR; ++ni)
                acc[mi][ni] = __builtin_amdgcn_mfma_f32_16x16x32_bf16(af[mi], bf[ni], acc[mi][ni], 0, 0, 0);
        __builtin_amdgcn_s_setprio(0);
        __builtin_amdgcn_sched_barrier(0);
        __builtin_amdgcn_s_barrier();
        bf16x8 af2[4];
        #pragma unroll
        for (int mi = 0; mi < 4; ++mi)
            af2[mi] = *(const bf16x8*)(ra + (wm * 8 + 4 + mi) * 512 + lane * 8);
        if (pre) stageB(i + 2, r2);
        __builtin_amdgcn_s_barrier();
        asm volatile("s_waitcnt lgkmcnt(0)" ::: "memory");
        __builtin_amdgcn_sched_barrier(0);
        __builtin_amdgcn_s_setprio(1);
        #pragma unroll
        for (int mi = 0; mi < 4; ++mi)
            #pragma unroll
            for (int ni = 0; ni < NR; ++ni)
                acc[4 + mi][ni] = __builtin_amdgcn_mfma_f32_16x16x32_bf16(af2[mi], bf[ni], acc[4 + mi][ni], 0, 0, 0);
        __builtin_amdgcn_s_setprio(0);
        __builtin_amdgcn_sched_barrier(0);
        if (i + 1 < nIter) {
            if (pre) {
                if constexpr (BN == 256) asm volatile("s_waitcnt vmcnt(4)" ::: "memory");
                else                     asm volatile("s_waitcnt vmcnt(3)" ::: "memory");
            } else {
                asm volatile("s_waitcnt vmcnt(0)" ::: "memory");
            }
            __builtin_amdgcn_sched_barrier(0);
            __builtin_amdgcn_s_barrier();
        }
        ++r; if (r >= 3) r = 0;
    }
    const int l15 = lane & 15, l4 = lane >> 4;
    #pragma unroll
    for (int mi = 0; mi < 8; ++mi) {
        #pragma unroll
        for (int ni = 0; ni < NR; ++ni) {
            const long grow0 = m0 + wm * 128 + mi * 16 + l4 * 4;
            const long gcol  = n0 + wn * (BN / 4) + ni * 16 + l15;
            if constexpr (EPI == 3) {
                #pragma unroll
                for (int j = 0; j < 4; ++j) {
                    const long idx = (grow0 + j) * 1024 + gcol;
                    ((float*)C)[idx] = base[idx] + acc[mi][ni][j] * rs[grow0 + j];
                }
            } else {  // EPI == 6
                const int sec = (int)(n0 >> 10);
                if (sec == 0) {
                    #pragma unroll
                    for (int j = 0; j < 4; ++j)
                        ((u16*)C)[(grow0 + j) * 1024 + gcol] = f2bf(acc[mi][ni][j]);
                } else if (sec == 1) {
                    const long col = gcol - 1024;
                    u16 pkv[4] = { f2bf(acc[mi][ni][0]), f2bf(acc[mi][ni][1]),
                                   f2bf(acc[mi][ni][2]), f2bf(acc[mi][ni][3]) };
                    const long idx = (grow0 >> 11) * 2097152 + col * 2048 + (grow0 & 2047);
                    *(uint2*)&((u16*)Cx)[idx] = *(uint2*)pkv;
                } else {
                    #pragma unroll
                    for (int j = 0; j < 4; ++j)
                        ((u16*)Cy)[(grow0 + j) * 1024 + (gcol - 2048)] = f2bf(acc[mi][ni][j]);
                }
            }
        }
    }
}

// ---------------------------------------------------------------------------
// bf16 NT MFMA GEMM, 128xBN tile, BK=32, 256 threads (2x2 waves).
// 3-STAGE LDS PIPELINE, 2 TILES IN FLIGHT. (unchanged)
// ---------------------------------------------------------------------------
template<int BN, int EPI, bool SWZ>
__global__ void __launch_bounds__(256) mfma_nt(
    const u16* __restrict__ A, long zAb, long zAh,
    const u16* __restrict__ B, long zBb, long zBh,
    void* __restrict__ C, long zCb, long zCh,
    void* __restrict__ Cx, void* __restrict__ Cy,
    int K, int lda, int ldb, int ldc, float alpha, int nH, int nsplit,
    const float* __restrict__ base, const float* __restrict__ rs,
    const float* __restrict__ accB, float* __restrict__ OT,
    long zOT, int ldt)
{
    constexpr int NR = BN / 32;
    constexpr int ABUF = 128 * 32;
    constexpr int BBUF = BN * 32;
    __shared__ __align__(16) u16 sh[3 * (ABUF + BBUF)];
    u16* const Ab0 = sh;
    u16* const Bb0 = sh + 3 * ABUF;
    int bx, by, bz;
    if constexpr (SWZ) {
        const int gx = gridDim.x, gy = gridDim.y;
        const int lin = blockIdx.x + gx * blockIdx.y;
        const int xcd = lin & 7, c = lin >> 3;
        const int LBY = gy >> 3;
        const int SPB = 4 * LBY;
        const int sc = c / SPB, rr = c - sc * SPB;
        const int byl = rr >> 2, bxl = rr & 3;
        by = xcd * LBY + byl;
        bx = sc * 4 + bxl;
        bz = 0;
    } else {
        bx = blockIdx.x; by = blockIdx.y; bz = blockIdx.z;
    }
    const int t = threadIdx.x;
    const int lane = t & 63, w = t >> 6;
    const int wr = w >> 1, wc = w & 1;
    const int slab = bz / nsplit, ks = bz - slab * nsplit;
    const int b = slab / nH, h = slab - b * nH;
    const int kchunk = K / nsplit;
    const int kbeg = ks * kchunk, kend = kbeg + kchunk;
    const long m0 = (long)by * 128;
    const long n0 = (long)bx * BN;
    const int frow = lane & 15, fko = (lane >> 4) * 8;
    const u16* gaA = A + zAb * b + zAh * h + (m0 + 32 * w + frow) * lda + fko;
    const u16* gbB;
    if constexpr (BN == 128) gbB = B + zBb * b + zBh * h + (n0 + 32 * w + frow) * ldb + fko;
    else                     gbB = B + zBb * b + zBh * h + (n0 + 16 * w + frow) * ldb + fko;

    auto stage = [&](int kk, int p) {
        u16* ap = Ab0 + p * ABUF;
        u16* bp = Bb0 + p * BBUF;
        GLD(gaA + kk, ap + 2 * w * 512);
        GLD(gaA + 16L * lda + kk, ap + (2 * w + 1) * 512);
        if constexpr (BN == 128) {
            GLD(gbB + kk, bp + 2 * w * 512);
            GLD(gbB + 16L * ldb + kk, bp + (2 * w + 1) * 512);
        } else {
            GLD(gbB + kk, bp + w * 512);
        }
    };

    const int nIter = (kend - kbeg) >> 5;
    f32x4 acc[4][NR] = {};
    stage(kbeg, 0);
    if (nIter > 1) stage(kbeg + 32, 1);
    int cur = 0;
    for (int i = 0; i < nIter; ++i) {
        if (i + 2 < nIter) {
            int p2 = cur + 2; if (p2 >= 3) p2 -= 3;
            stage(kbeg + (i + 2) * 32, p2);
            if constexpr (BN == 128) asm volatile("s_waitcnt vmcnt(8)" ::: "memory");
            else                     asm volatile("s_waitcnt vmcnt(6)" ::: "memory");
        } else if (i + 1 < nIter) {
            if constexpr (BN == 128) asm volatile("s_waitcnt vmcnt(4)" ::: "memory");
            else                     asm volatile("s_waitcnt vmcnt(3)" ::: "memory");
        } else {
            asm volatile("s_waitcnt vmcnt(0)" ::: "memory");
        }
        __builtin_amdgcn_sched_barrier(0);
        __builtin_amdgcn_s_barrier();
        __builtin_amdgcn_sched_barrier(0);
        const u16* ap = Ab0 + cur * ABUF;
        const u16* bp = Bb0 + cur * BBUF;
        bf16x8 af[4], bfr[NR];
        #pragma unroll
        for (int m = 0; m < 4; ++m)
            af[m] = *(const bf16x8*)(ap + (wr * 4 + m) * 512 + lane * 8);
        #pragma unroll
        for (int n = 0; n < NR; ++n)
            bfr[n] = *(const bf16x8*)(bp + (wc * NR + n) * 512 + lane * 8);
        asm volatile("s_waitcnt lgkmcnt(0)" ::: "memory");
        __builtin_amdgcn_sched_barrier(0);
        __builtin_amdgcn_s_barrier();
        #pragma unroll
        for (int m = 0; m < 4; ++m)
            #pragma unroll
            for (int n = 0; n < NR; ++n)
                acc[m][n] = __builtin_amdgcn_mfma_f32_16x16x32_bf16(af[m], bfr[n], acc[m][n], 0, 0, 0);
        cur = (cur == 2) ? 0 : cur + 1;
    }
    const long Coff = zCb * b + zCh * h;
    const int l15 = lane & 15, l4 = lane >> 4;
    #pragma unroll
    for (int m = 0; m < 4; ++m) {
        #pragma unroll
        for (int n = 0; n < NR; ++n) {
            #pragma unroll
            for (int j = 0; j < 4; ++j) {
                const long grow = m0 + wr * 64 + m * 16 + l4 * 4 + j;
                const long gcol = n0 + wc * (BN / 2) + n * 16 + l15;
                const float v = acc[m][n][j] * alpha;
                if constexpr (EPI == 3) {
                    const long idx = grow * ldc + gcol;
                    ((float*)C)[idx] = base[idx] + v * rs[grow];
                } else if constexpr (EPI == 5) {
                    const long idx = Coff + grow * ldc + gcol;
                    ((float*)C)[idx] = 0.7f * base[idx] + 0.3f * v;
                    const long tidx = zOT * b + gcol * (long)ldt + grow;
                    OT[tidx] = 0.7f * accB[tidx] + 0.3f * v;
                } else if constexpr (EPI == 7) {
                    const int sec = (int)(n0 >> 10);
                    if (sec == 0) ((u16*)C)[grow * 1024 + gcol] = f2bf(v);            // Q_conv
                    else if (sec == 1) ((u16*)Cx)[grow * 1024 + (gcol - 1024)] = f2bf(v); // K_emer
                    else {
                        const long col = gcol - 2048;                                  // VT_emer
                        ((u16*)Cy)[(grow >> 8) * 262144 + col * 256 + (grow & 255)] = f2bf(v);
                    }
                }
            }
        }
    }
}

__global__ void __launch_bounds__(256) rowmean_sig_kernel(
    const float* __restrict__ X, int len, float invlen,
    const float* __restrict__ alpha_p, float* __restrict__ OUT)
{
    const int row = blockIdx.x * 4 + (threadIdx.x >> 6);
    const int lane = threadIdx.x & 63;
    const float* xr = X + (long)row * len;
    float s = 0.0f;
    for (int k = lane; k < len; k += 64) s += xr[k];
    for (int o = 32; o > 0; o >>= 1) s += __shfl_xor(s, o);
    if (lane == 0) OUT[row] = sigmoidf_((*alpha_p) * s * invlen);
}

#define MFMA_TAIL nullptr, nullptr, nullptr, nullptr, 0L, 0

extern "C" void kernel_launch(void* const* d_in, const int* in_sizes, int n_in,
                              void* d_out, int out_size, void* d_ws, size_t ws_size,
                              hipStream_t stream)
{
    (void)in_sizes; (void)n_in; (void)out_size; (void)ws_size;
    const float* o_micro    = (const float*)d_in[0];
    const float* o_macro    = (const float*)d_in[1];
    const float* r_conv_acc = (const float*)d_in[2];
    const float* r_emer_acc = (const float*)d_in[3];
    const float* ln_u_w = (const float*)d_in[4];
    const float* ln_u_b = (const float*)d_in[5];
    const float* bw_u   = (const float*)d_in[6];
    const float* ln_m_w = (const float*)d_in[7];
    const float* ln_m_b = (const float*)d_in[8];
    const float* bw_m   = (const float*)d_in[9];
    const float* gu_w   = (const float*)d_in[10];
    const float* gu_b   = (const float*)d_in[11];
    const float* gm_w   = (const float*)d_in[12];
    const float* gm_b   = (const float*)d_in[13];
    const float* wq_c   = (const float*)d_in[14];
    const float* wk_c   = (const float*)d_in[15];
    const float* wv_c   = (const float*)d_in[16];
    const float* wo_c   = (const float*)d_in[17];
    const float* wq_e   = (const float*)d_in[18];
    const float* wk_e   = (const float*)d_in[19];
    const float* wv_e   = (const float*)d_in[20];
    const float* wo_e   = (const float*)d_in[21];
    const float* res_alpha = (const float*)d_in[22];

    float* out = (float*)d_out;
    float* out_micro = out;              // (4,2048,1024)
    float* out_macro = out + 8388608;    // (4,256,1024)
    float* out_rconv = out + 9437184;    // (4,256,2048)
    float* out_remer = out + 11534336;   // (4,2048,256)

    // workspace (f32 slot offsets; bf16 buffers use 2 el/slot)
    float* ws = (float*)d_ws;
    u16* OUb = (u16*)ws;                       // 8388608 bf16 (normed micro)
    u16* OMb = (u16*)(ws + 4194304);           // 1048576 bf16 (normed macro)
    u16* WB  = (u16*)(ws + 4718592);           // 8 x 1048576 bf16 weights
                                               //   [wk_c wv_c wq_e | wq_c wk_e wv_e | wo_c wo_e]
    u16* Kcb = (u16*)(ws + 8912896);           // conv K (8192x1024) -> later CTe
    u16* VTc = (u16*)(ws + 13107200);          // conv V^T [b][h][64][2048]
    u16* Qeb = (u16*)(ws + 17301504);          // emer Q (8192x1024)
    u16* Qcb = (u16*)(ws + 21495808);          // conv Q (1024x1024)
    u16* Keb = (u16*)(ws + 22020096);          // emer K (1024x1024)
    u16* VTe = (u16*)(ws + 22544384);          // emer V^T [b][h][64][256]
    u16* PNu = (u16*)(ws + 23068672);          // pairnormed micro (8.4M bf16)
    float* CT = ws + 27262976;                 // early: PNm; later conv ctx bf16
    float* GU = ws + 28311552;                 // 8192
    float* GM = GU + 8192;                     // 1024
    float* RCS = GM + 1024;                    // 1024
    float* RES = RCS + 1024;                   // 8192
    u16* PNm = (u16*)CT;
    u16* CTc = (u16*)CT;                       // conv ctx bf16 (1024x1024)
    u16* CTe = Kcb;                            // emer ctx bf16 (8192x1024)

    // 1. weights -> bf16, reordered for fused projections
    wconv_kernel<<<dim3(1024, 8), 256, 0, stream>>>(wk_c, wv_c, wq_e, wq_c, wk_e, wv_e, wo_c, wo_e, WB);
    // 2. balance norms + gates + fused pairnorm (wave-per-row)
    norm_gate_kernel<<<2048, 256, 0, stream>>>(o_micro, ln_u_w, ln_u_b, bw_u, gu_w, gu_b, OUb, PNu, GU);
    norm_gate_kernel<<<256, 256, 0, stream>>>(o_macro, ln_m_w, ln_m_b, bw_m, gm_w, gm_b, OMb, PNm, GM);
    // 3. resonance GEMM + 0.7/0.3 blend + transposed write
    mfma_nt<128, 5, false><<<dim3(16, 2, 4), 256, 0, stream>>>(
        PNm, 262144L, 0L, PNu, 2097152L, 0L, out_rconv, 524288L, 0L, nullptr, nullptr,
        1024, 1024, 1024, 2048, 1.0f / 512.0f, 1, 1,
        r_conv_acc, nullptr, r_emer_acc, out_remer, 524288L, 256);
    // 4. resonance scalars
    rowmean_sig_kernel<<<256, 256, 0, stream>>>(out_rconv, 2048, 1.0f / 2048.0f, res_alpha, RCS);
    rowmean_sig_kernel<<<2048, 256, 0, stream>>>(out_remer, 256, 1.0f / 256.0f, res_alpha, RES);
    // 5. fused micro-side projections: [K_conv | VT_conv | Q_emer]
    mfma8<256, 6><<<dim3(12, 32), 512, 0, stream>>>(
        OUb, WB, Kcb, VTc, Qeb, 1024, 1024, 1024, nullptr, nullptr);
    // 6. fused macro-side projections: [Q_conv | K_emer | VT_emer]
    mfma_nt<128, 7, true><<<dim3(24, 8, 1), 256, 0, stream>>>(
        OMb, 0L, 0L, WB + 3 * 1048576, 0L, 0L, Qcb, 0L, 0L, Keb, VTe,
        1024, 1024, 1024, 1024, 1.0f, 1, 1, MFMA_TAIL);
    // 7. conv fused flash attention (q from macro, kv from micro)
    attn_flash<<<dim3(4, 16, 4), 256, 0, stream>>>(
        Qcb, Kcb, VTc, GM, GU, CTc, 256, 2048, 2097152L);
    // 8. conv out-proj + residual + r_conv_scalar -> o_macro_new
    mfma_nt<128, 3, false><<<dim3(8, 8, 1), 256, 0, stream>>>(
        CTc, 0L, 0L, WB + 6 * 1048576, 0L, 0L, out_macro, 0L, 0L, nullptr, nullptr,
        1024, 1024, 1024, 1024, 1.0f, 1, 1, o_macro, RCS, nullptr, nullptr, 0L, 0);
    // 9. emer fused flash attention (q from micro, kv from macro)
    attn_flash<<<dim3(32, 16, 4), 256, 0, stream>>>(
        Qeb, Keb, VTe, GU, GM, CTe, 2048, 256, 262144L);
    // 10. emer out-proj + residual + r_emer_scalar -> o_micro_new
    mfma8<128, 3><<<dim3(8, 32), 512, 0, stream>>>(
        CTe, WB + 7 * 1048576, out_micro, nullptr, nullptr,
        1024, 1024, 1024, o_micro, RES);
}